// Round 1
// baseline (492.616 us; speedup 1.0000x reference)
//
#include <hip/hip_runtime.h>
#include <hip/hip_bf16.h>
#include <stdint.h>

// Problem constants: B=4, S=2048, D=1024, H=16, DK=64
static constexpr int kS  = 2048;
static constexpr int kH  = 16;
static constexpr int kDK = 64;
static constexpr int kD  = 1024;
static constexpr int kB  = 4;
static constexpr int kM  = kB * kS;   // 8192 tokens

typedef __bf16 bf16;
typedef __attribute__((ext_vector_type(8))) __bf16 bf16x8;
typedef __attribute__((ext_vector_type(4))) __bf16 bf16x4;
typedef __attribute__((ext_vector_type(4))) float f32x4;

__device__ __forceinline__ void gload_lds16(const bf16* g, bf16* l) {
  __builtin_amdgcn_global_load_lds((__attribute__((address_space(1))) void*)(void*)g,
                                   (__attribute__((address_space(3))) void*)l, 16, 0, 0);
}

// ---------------- fp32 -> bf16 convert (vectorized) ----------------
__global__ void cvt_f32_bf16(const float* __restrict__ in, bf16* __restrict__ out, int n4) {
  int i = blockIdx.x * blockDim.x + threadIdx.x;
  if (i >= n4) return;
  float4 v = reinterpret_cast<const float4*>(in)[i];
  bf16x4 o;
  o[0] = (bf16)v.x; o[1] = (bf16)v.y; o[2] = (bf16)v.z; o[3] = (bf16)v.w;
  reinterpret_cast<bf16x4*>(out)[i] = o;
}

// ---------------- GEMM: out[m][n] = sum_k A[m][k] * W[n][k] ----------------
// A: [M][K] bf16 row-major. W: [N][K] bf16 row-major (B^T layout).
// mode 0: write bf16 permuted to [B][H][S][DK]  (token m -> (b,s), col n -> (h,dk))
// mode 1: write fp32 linear [M][1024] to dst
__global__ __launch_bounds__(256) void gemm_bt(const bf16* __restrict__ A,
                                               const bf16* __restrict__ W,
                                               void* __restrict__ dst,
                                               int K, int mode) {
  __shared__ __align__(16) bf16 As[128 * 32];
  __shared__ __align__(16) bf16 Bs[128 * 32];

  const int tid = threadIdx.x;
  const int l   = tid & 63;
  const int w   = tid >> 6;                 // wave 0..3
  const int brow = blockIdx.x * 128;
  const int bcol = blockIdx.y * 128;
  const int wr = (w >> 1) * 64;             // wave row offset in tile
  const int wc = (w & 1) * 64;              // wave col offset in tile

  f32x4 acc[4][4] = {};

  const int lrow = l >> 2;                  // 0..15 within 16-row chunk
  const int lcol = (l & 3) * 8;             // element col within BK=32

  const int fr  = l & 15;
  const int fk  = (l >> 4) * 8;

  const int nk = K >> 5;
  for (int kt = 0; kt < nk; ++kt) {
    const int k0 = kt << 5;
#pragma unroll
    for (int c2 = 0; c2 < 2; ++c2) {
      const int c = w * 2 + c2;             // chunk 0..7 (16 rows each)
      const int r = c * 16 + lrow;
      gload_lds16(A + (size_t)(brow + r) * K + k0 + lcol, &As[c * 512]);
      gload_lds16(W + (size_t)(bcol + r) * K + k0 + lcol, &Bs[c * 512]);
    }
    __syncthreads();
    bf16x8 af[4], bfm[4];
#pragma unroll
    for (int m = 0; m < 4; ++m) af[m]  = *(const bf16x8*)&As[(wr + m * 16 + fr) * 32 + fk];
#pragma unroll
    for (int n = 0; n < 4; ++n) bfm[n] = *(const bf16x8*)&Bs[(wc + n * 16 + fr) * 32 + fk];
#pragma unroll
    for (int m = 0; m < 4; ++m)
#pragma unroll
      for (int n = 0; n < 4; ++n)
        acc[m][n] = __builtin_amdgcn_mfma_f32_16x16x32_bf16(af[m], bfm[n], acc[m][n], 0, 0, 0);
    __syncthreads();
  }

  const int frow = (l >> 4) * 4;
  if (mode == 0) {
    bf16* out = (bf16*)dst;
#pragma unroll
    for (int m = 0; m < 4; ++m) {
#pragma unroll
      for (int n = 0; n < 4; ++n) {
        const int col = bcol + wc + n * 16 + fr;
        const int h = col >> 6, dk = col & 63;
#pragma unroll
        for (int r = 0; r < 4; ++r) {
          const int row = brow + wr + m * 16 + frow + r;   // token index
          const int b = row >> 11, s = row & (kS - 1);
          out[((((size_t)b * kH + h) * kS + s) << 6) + dk] = (bf16)acc[m][n][r];
        }
      }
    }
  } else {
    float* out = (float*)dst;
#pragma unroll
    for (int m = 0; m < 4; ++m) {
#pragma unroll
      for (int n = 0; n < 4; ++n) {
        const int col = bcol + wc + n * 16 + fr;
#pragma unroll
        for (int r = 0; r < 4; ++r) {
          const int row = brow + wr + m * 16 + frow + r;
          out[(size_t)row * kD + col] = acc[m][n][r];
        }
      }
    }
  }
}

// ---------------- RoPE (interleaved pairs), in-place on Q and K ----------------
// Layout [BH][S][DK]; np = pairs per tensor = 64*2048*32
__global__ void rope_kernel(bf16* __restrict__ Q, bf16* __restrict__ Kb,
                            const int* __restrict__ pos, int np) {
  int idx = blockIdx.x * blockDim.x + threadIdx.x;
  if (idx >= 2 * np) return;
  bf16* T = (idx < np) ? Q : Kb;
  int id = (idx < np) ? idx : idx - np;
  const int i = id & 31;                    // freq index 0..31
  const int s = (id >> 5) & (kS - 1);       // sequence position
  const float p = (float)pos[s];
  // freq = 10000^(-2i/64) = exp(-i * ln(10000)/32)
  const float freq = __expf(-0.2878231366242557f * (float)i);
  const float f = p * freq;
  float sn, cs;
  sincosf(f, &sn, &cs);
  const size_t off = (size_t)id * 2;
  const float e = (float)T[off], o = (float)T[off + 1];
  T[off]     = (bf16)(e * cs - o * sn);
  T[off + 1] = (bf16)(o * cs + e * sn);
}

// ---------------- causal flash attention ----------------
// Q,K,V: [BH][S][DK] bf16 (rope already applied). O: [B][S][D] bf16.
// grid: (BH, S/64); block 256 = 4 waves; wave w handles 16 q-rows.
__global__ __launch_bounds__(256) void attn_fwd(const bf16* __restrict__ Q,
                                                const bf16* __restrict__ Kb,
                                                const bf16* __restrict__ Vb,
                                                bf16* __restrict__ O) {
  const int bh = blockIdx.x;
  const int qt = blockIdx.y;
  const int tid = threadIdx.x;
  const int l = tid & 63;
  const int w = tid >> 6;

  __shared__ __align__(16) bf16 Ks[32 * 64];   // [kv][dk]
  __shared__ __align__(16) bf16 Vt[64 * 32];   // [dk][kv] (transposed)
  __shared__ __align__(16) bf16 Pl[4][16 * 32];

  const int q0 = qt * 64 + w * 16;
  const int fr  = l & 15;
  const int fkg = l >> 4;                      // 0..3
  const size_t base = (size_t)bh * kS * kDK;

  // Q fragments (A operand): row = fr, k = kc*32 + fkg*8 + j
  bf16x8 aq[2];
#pragma unroll
  for (int kc = 0; kc < 2; ++kc)
    aq[kc] = *(const bf16x8*)&Q[base + (size_t)(q0 + fr) * kDK + kc * 32 + fkg * 8];

  f32x4 ao[4] = {};
  float m_r[4], l_r[4];
#pragma unroll
  for (int r = 0; r < 4; ++r) { m_r[r] = -1e30f; l_r[r] = 0.f; }

  const int nt = 2 * qt + 2;
  const int srow = tid >> 3;                   // 0..31
  const int scol = (tid & 7) * 8;              // 0..56

  for (int j = 0; j < nt; ++j) {
    // ---- stage K (row-major) and V (transposed) tiles ----
    const size_t kvoff = base + (size_t)(j * 32 + srow) * kDK + scol;
    bf16x8 k8 = *(const bf16x8*)&Kb[kvoff];
    *(bf16x8*)&Ks[srow * 64 + scol] = k8;
    bf16x8 v8 = *(const bf16x8*)&Vb[kvoff];
#pragma unroll
    for (int e = 0; e < 8; ++e) Vt[(scol + e) * 32 + srow] = v8[e];
    __syncthreads();

    if (j * 32 <= q0 + 15) {                   // wave has unmasked work in this tile
      // ---- scores: 16 x 32 ----
      f32x4 sc[2] = {};
#pragma unroll
      for (int nf = 0; nf < 2; ++nf)
#pragma unroll
        for (int kc = 0; kc < 2; ++kc) {
          bf16x8 bk = *(const bf16x8*)&Ks[(nf * 16 + fr) * 64 + kc * 32 + fkg * 8];
          sc[nf] = __builtin_amdgcn_mfma_f32_16x16x32_bf16(aq[kc], bk, sc[nf], 0, 0, 0);
        }
      // ---- online softmax (rows live in lanes with same l>>4) ----
      float p0s[4], p1s[4];
#pragma unroll
      for (int r = 0; r < 4; ++r) {
        const int qg = q0 + fkg * 4 + r;
        float s0 = sc[0][r] * 0.125f;
        float s1 = sc[1][r] * 0.125f;
        if (j * 32 + fr > qg)      s0 = -INFINITY;
        if (j * 32 + 16 + fr > qg) s1 = -INFINITY;
        float mx = fmaxf(s0, s1);
#pragma unroll
        for (int d = 1; d < 16; d <<= 1) mx = fmaxf(mx, __shfl_xor(mx, d));
        const float mnew = fmaxf(m_r[r], mx);
        const float sf = __expf(m_r[r] - mnew);
        const float p0 = __expf(s0 - mnew);
        const float p1 = __expf(s1 - mnew);
        float rs = p0 + p1;
#pragma unroll
        for (int d = 1; d < 16; d <<= 1) rs += __shfl_xor(rs, d);
        l_r[r] = l_r[r] * sf + rs;
        m_r[r] = mnew;
        p0s[r] = p0; p1s[r] = p1;
#pragma unroll
        for (int n = 0; n < 4; ++n) ao[n][r] *= sf;
      }
      // ---- P -> LDS (per-wave), reload as A fragment ----
#pragma unroll
      for (int r = 0; r < 4; ++r) {
        Pl[w][(fkg * 4 + r) * 32 + fr]      = (bf16)p0s[r];
        Pl[w][(fkg * 4 + r) * 32 + 16 + fr] = (bf16)p1s[r];
      }
      bf16x8 pa = *(const bf16x8*)&Pl[w][fr * 32 + fkg * 8];
      // ---- PV: P(16x32) @ V(32x64) ----
#pragma unroll
      for (int n = 0; n < 4; ++n) {
        bf16x8 bv = *(const bf16x8*)&Vt[(n * 16 + fr) * 32 + fkg * 8];
        ao[n] = __builtin_amdgcn_mfma_f32_16x16x32_bf16(pa, bv, ao[n], 0, 0, 0);
      }
    }
    __syncthreads();
  }

  // ---- write O in [B][S][D] layout ----
  const int b = bh >> 4, h = bh & 15;
#pragma unroll
  for (int n = 0; n < 4; ++n)
#pragma unroll
    for (int r = 0; r < 4; ++r) {
      const int qg = q0 + fkg * 4 + r;
      const float ov = ao[n][r] / l_r[r];
      O[((size_t)(b * kS + qg) << 10) + h * 64 + n * 16 + fr] = (bf16)ov;
    }
}

// ---------------- launch ----------------
extern "C" void kernel_launch(void* const* d_in, const int* in_sizes, int n_in,
                              void* d_out, int out_size, void* d_ws, size_t ws_size,
                              hipStream_t stream) {
  const float* x  = (const float*)d_in[0];
  const float* wq = (const float*)d_in[1];
  const float* wk = (const float*)d_in[2];
  const float* wv = (const float*)d_in[3];
  const float* wo = (const float*)d_in[4];
  const int* pos  = (const int*)d_in[5];

  bf16* xb  = (bf16*)d_ws;                          // [8192][1024]
  bf16* wqb = xb  + (size_t)kM * kD;
  bf16* wkb = wqb + (size_t)kD * kD;
  bf16* wvb = wkb + (size_t)kD * kD;
  bf16* wob = wvb + (size_t)kD * kD;
  bf16* Qb  = wob + (size_t)kD * kD;                // [64][2048][64]
  bf16* Kbf = Qb  + (size_t)64 * kS * kDK;
  bf16* Vbf = Kbf + (size_t)64 * kS * kDK;
  bf16* Ob  = Vbf + (size_t)64 * kS * kDK;          // [8192][1024]

  // converts
  {
    int n4 = kM * kD / 4;
    cvt_f32_bf16<<<(n4 + 255) / 256, 256, 0, stream>>>(x, xb, n4);
    n4 = kD * kD / 4;
    cvt_f32_bf16<<<(n4 + 255) / 256, 256, 0, stream>>>(wq, wqb, n4);
    cvt_f32_bf16<<<(n4 + 255) / 256, 256, 0, stream>>>(wk, wkb, n4);
    cvt_f32_bf16<<<(n4 + 255) / 256, 256, 0, stream>>>(wv, wvb, n4);
    cvt_f32_bf16<<<(n4 + 255) / 256, 256, 0, stream>>>(wo, wob, n4);
  }

  dim3 gg(kM / 128, kD / 128);   // 64 x 8
  gemm_bt<<<gg, 256, 0, stream>>>(xb, wqb, Qb, kD, 0);
  gemm_bt<<<gg, 256, 0, stream>>>(xb, wkb, Kbf, kD, 0);
  gemm_bt<<<gg, 256, 0, stream>>>(xb, wvb, Vbf, kD, 0);

  const int np = 64 * kS * 32;
  rope_kernel<<<(2 * np) / 256, 256, 0, stream>>>(Qb, Kbf, pos, np);

  dim3 ga(64, kS / 64);          // (bh, qtile)
  attn_fwd<<<ga, 256, 0, stream>>>(Qb, Kbf, Vbf, Ob);

  gemm_bt<<<gg, 256, 0, stream>>>(Ob, wob, d_out, kD, 1);
}

// Round 3
// 366.935 us; speedup vs baseline: 1.3425x; 1.3425x over previous
//
#include <hip/hip_runtime.h>
#include <hip/hip_bf16.h>
#include <stdint.h>

// Problem constants: B=4, S=2048, D=1024, H=16, DK=64
static constexpr int kS  = 2048;
static constexpr int kH  = 16;
static constexpr int kDK = 64;
static constexpr int kD  = 1024;
static constexpr int kB  = 4;
static constexpr int kM  = kB * kS;   // 8192 tokens

typedef __bf16 bf16;
typedef __attribute__((ext_vector_type(8))) __bf16 bf16x8;
typedef __attribute__((ext_vector_type(4))) __bf16 bf16x4;
typedef __attribute__((ext_vector_type(4))) float f32x4;

__device__ __forceinline__ void gload_lds16(const bf16* g, bf16* l) {
  __builtin_amdgcn_global_load_lds((__attribute__((address_space(1))) void*)(void*)g,
                                   (__attribute__((address_space(3))) void*)l, 16, 0, 0);
}

// ---------------- fp32 -> bf16 convert (vectorized) ----------------
__global__ void cvt_f32_bf16(const float* __restrict__ in, bf16* __restrict__ out, int n4) {
  int i = blockIdx.x * blockDim.x + threadIdx.x;
  if (i >= n4) return;
  float4 v = reinterpret_cast<const float4*>(in)[i];
  bf16x4 o;
  o[0] = (bf16)v.x; o[1] = (bf16)v.y; o[2] = (bf16)v.z; o[3] = (bf16)v.w;
  reinterpret_cast<bf16x4*>(out)[i] = o;
}

// ---------------- GEMM: out[m][n] = sum_k A[m][k] * W[n][k] ----------------
__global__ __launch_bounds__(256) void gemm_bt(const bf16* __restrict__ A,
                                               const bf16* __restrict__ W,
                                               void* __restrict__ dst,
                                               int K, int mode) {
  __shared__ __align__(16) bf16 As[128 * 32];
  __shared__ __align__(16) bf16 Bs[128 * 32];

  const int tid = threadIdx.x;
  const int l   = tid & 63;
  const int w   = tid >> 6;                 // wave 0..3
  const int brow = blockIdx.x * 128;
  const int bcol = blockIdx.y * 128;
  const int wr = (w >> 1) * 64;
  const int wc = (w & 1) * 64;

  f32x4 acc[4][4] = {};

  const int lrow = l >> 2;
  const int lcol = (l & 3) * 8;

  const int fr  = l & 15;
  const int fk  = (l >> 4) * 8;

  const int nk = K >> 5;
  for (int kt = 0; kt < nk; ++kt) {
    const int k0 = kt << 5;
#pragma unroll
    for (int c2 = 0; c2 < 2; ++c2) {
      const int c = w * 2 + c2;
      const int r = c * 16 + lrow;
      gload_lds16(A + (size_t)(brow + r) * K + k0 + lcol, &As[c * 512]);
      gload_lds16(W + (size_t)(bcol + r) * K + k0 + lcol, &Bs[c * 512]);
    }
    __syncthreads();
    bf16x8 af[4], bfm[4];
#pragma unroll
    for (int m = 0; m < 4; ++m) af[m]  = *(const bf16x8*)&As[(wr + m * 16 + fr) * 32 + fk];
#pragma unroll
    for (int n = 0; n < 4; ++n) bfm[n] = *(const bf16x8*)&Bs[(wc + n * 16 + fr) * 32 + fk];
#pragma unroll
    for (int m = 0; m < 4; ++m)
#pragma unroll
      for (int n = 0; n < 4; ++n)
        acc[m][n] = __builtin_amdgcn_mfma_f32_16x16x32_bf16(af[m], bfm[n], acc[m][n], 0, 0, 0);
    __syncthreads();
  }

  const int frow = (l >> 4) * 4;
  if (mode == 0) {
    bf16* out = (bf16*)dst;
#pragma unroll
    for (int m = 0; m < 4; ++m) {
#pragma unroll
      for (int n = 0; n < 4; ++n) {
        const int col = bcol + wc + n * 16 + fr;
        const int h = col >> 6, dk = col & 63;
#pragma unroll
        for (int r = 0; r < 4; ++r) {
          const int row = brow + wr + m * 16 + frow + r;
          const int b = row >> 11, s = row & (kS - 1);
          out[((((size_t)b * kH + h) * kS + s) << 6) + dk] = (bf16)acc[m][n][r];
        }
      }
    }
  } else {
    float* out = (float*)dst;
#pragma unroll
    for (int m = 0; m < 4; ++m) {
#pragma unroll
      for (int n = 0; n < 4; ++n) {
        const int col = bcol + wc + n * 16 + fr;
#pragma unroll
        for (int r = 0; r < 4; ++r) {
          const int row = brow + wr + m * 16 + frow + r;
          out[(size_t)row * kD + col] = acc[m][n][r];
        }
      }
    }
  }
}

// ---------------- RoPE (interleaved pairs), in-place on Q and K ----------------
__global__ void rope_kernel(bf16* __restrict__ Q, bf16* __restrict__ Kb,
                            const int* __restrict__ pos, int np) {
  int idx = blockIdx.x * blockDim.x + threadIdx.x;
  if (idx >= 2 * np) return;
  bf16* T = (idx < np) ? Q : Kb;
  int id = (idx < np) ? idx : idx - np;
  const int i = id & 31;
  const int s = (id >> 5) & (kS - 1);
  const float p = (float)pos[s];
  const float freq = __expf(-0.2878231366242557f * (float)i);
  const float f = p * freq;
  float sn, cs;
  sincosf(f, &sn, &cs);
  const size_t off = (size_t)id * 2;
  const float e = (float)T[off], o = (float)T[off + 1];
  T[off]     = (bf16)(e * cs - o * sn);
  T[off + 1] = (bf16)(o * cs + e * sn);
}

// ---------------- causal flash attention v2 ----------------
// Q,K,V: [BH][S][DK] bf16. O: [B][S][D] bf16.
// grid: (BH, S/64); block 256 = 4 waves; wave w owns 16 q-rows.
// KVBLK=64; K/Vt/P LDS XOR-swizzled (elem ^= (row&7)<<3).
__global__ __launch_bounds__(256) void attn_fwd(const bf16* __restrict__ Q,
                                                const bf16* __restrict__ Kb,
                                                const bf16* __restrict__ Vb,
                                                bf16* __restrict__ O) {
  const int bh = blockIdx.x;
  const int qt = (int)gridDim.y - 1 - (int)blockIdx.y;   // heavy blocks first
  const int tid = threadIdx.x;
  const int l = tid & 63;
  const int w = tid >> 6;

  __shared__ __align__(16) bf16 Ks[64 * 64];   // [kv][dk], swizzled
  __shared__ __align__(16) bf16 Vt[64 * 64];   // [dk][kv], swizzled
  __shared__ __align__(16) bf16 Pl[4][16 * 64];// per-wave [q][kv], swizzled

  const int q0 = qt * 64 + w * 16;
  const int fr  = l & 15;
  const int fkg = l >> 4;                      // 0..3
  const size_t base = (size_t)bh * kS * kDK;

  // Q fragments (A operand): row = fr, k = kc*32 + fkg*8 + j
  bf16x8 aq[2];
#pragma unroll
  for (int kc = 0; kc < 2; ++kc)
    aq[kc] = *(const bf16x8*)&Q[base + (size_t)(q0 + fr) * kDK + kc * 32 + fkg * 8];

  f32x4 ao[4] = {};
  float m_r[4], l_r[4];
#pragma unroll
  for (int r = 0; r < 4; ++r) { m_r[r] = -1e30f; l_r[r] = 0.f; }

  const int nt = qt + 1;

  // staging indices
  const int krow = tid >> 3;                   // 0..31 (+32 second pass)
  const int kcol = (tid & 7) * 8;              // element col
  const int dk0  = w * 16;                     // V: wave owns 16 dk cols; lane = kv

  bf16x8 kreg0, kreg1, vreg0, vreg1;
  {
    const size_t kb0 = base + (size_t)krow * kDK + kcol;
    kreg0 = *(const bf16x8*)&Kb[kb0];
    kreg1 = *(const bf16x8*)&Kb[kb0 + 32 * kDK];
    const size_t vb0 = base + (size_t)l * kDK + dk0;
    vreg0 = *(const bf16x8*)&Vb[vb0];
    vreg1 = *(const bf16x8*)&Vb[vb0 + 8];
  }

  for (int j = 0; j < nt; ++j) {
    // ---- write staged regs to LDS (swizzled) ----
    {
      const int r0 = krow, r1 = krow + 32;
      *(bf16x8*)&Ks[r0 * 64 + (kcol ^ ((r0 & 7) << 3))] = kreg0;
      *(bf16x8*)&Ks[r1 * 64 + (kcol ^ ((r1 & 7) << 3))] = kreg1;
#pragma unroll
      for (int e = 0; e < 8; ++e) {
        const int d0 = dk0 + e, d1 = dk0 + 8 + e;
        Vt[d0 * 64 + (l ^ ((d0 & 7) << 3))] = vreg0[e];
        Vt[d1 * 64 + (l ^ ((d1 & 7) << 3))] = vreg1[e];
      }
    }
    __syncthreads();

    // ---- prefetch next tile into regs (latency hides under compute) ----
    if (j + 1 < nt) {
      const size_t kb0 = base + (size_t)((j + 1) * 64 + krow) * kDK + kcol;
      kreg0 = *(const bf16x8*)&Kb[kb0];
      kreg1 = *(const bf16x8*)&Kb[kb0 + 32 * kDK];
      const size_t vb0 = base + (size_t)((j + 1) * 64 + l) * kDK + dk0;
      vreg0 = *(const bf16x8*)&Vb[vb0];
      vreg1 = *(const bf16x8*)&Vb[vb0 + 8];
    }

    const bool diag = (j == nt - 1);

    // ---- scores: 16 x 64 ----
    f32x4 sc[4] = {};
#pragma unroll
    for (int nf = 0; nf < 4; ++nf) {
      if (!diag || nf <= w) {
#pragma unroll
        for (int kc = 0; kc < 2; ++kc) {
          const int row = nf * 16 + fr;
          bf16x8 bk = *(const bf16x8*)&Ks[row * 64 + ((kc * 32 + fkg * 8) ^ ((row & 7) << 3))];
          sc[nf] = __builtin_amdgcn_mfma_f32_16x16x32_bf16(aq[kc], bk, sc[nf], 0, 0, 0);
        }
      }
    }

    // ---- online softmax (row r lives in lanes sharing fkg; cols = fr) ----
    float p[4][4];
#pragma unroll
    for (int r = 0; r < 4; ++r) {
      const int qloc = w * 16 + fkg * 4 + r;   // q row local to block
      float s[4];
#pragma unroll
      for (int nf = 0; nf < 4; ++nf) {
        s[nf] = sc[nf][r] * 0.125f;
        if (diag && (nf * 16 + fr) > qloc) s[nf] = -INFINITY;
      }
      float mx = fmaxf(fmaxf(s[0], s[1]), fmaxf(s[2], s[3]));
#pragma unroll
      for (int d = 1; d < 16; d <<= 1) mx = fmaxf(mx, __shfl_xor(mx, d));
      const float mnew = fmaxf(m_r[r], mx);
      const float sf = __expf(m_r[r] - mnew);
      float rs = 0.f;
#pragma unroll
      for (int nf = 0; nf < 4; ++nf) { p[nf][r] = __expf(s[nf] - mnew); rs += p[nf][r]; }
#pragma unroll
      for (int d = 1; d < 16; d <<= 1) rs += __shfl_xor(rs, d);
      l_r[r] = l_r[r] * sf + rs;
      m_r[r] = mnew;
#pragma unroll
      for (int n = 0; n < 4; ++n) ao[n][r] *= sf;
    }

    // ---- P -> per-wave LDS (swizzled), reload as A fragments ----
#pragma unroll
    for (int r = 0; r < 4; ++r) {
      const int qrow = fkg * 4 + r;
      const int sw = (qrow & 7) << 3;
#pragma unroll
      for (int nf = 0; nf < 4; ++nf)
        Pl[w][qrow * 64 + ((nf * 16 + fr) ^ sw)] = (bf16)p[nf][r];
    }
    bf16x8 pa[2];
#pragma unroll
    for (int kc2 = 0; kc2 < 2; ++kc2)
      pa[kc2] = *(const bf16x8*)&Pl[w][fr * 64 + ((kc2 * 32 + fkg * 8) ^ ((fr & 7) << 3))];

    // ---- PV: P(16x64) @ V(64x64) ----
#pragma unroll
    for (int kc2 = 0; kc2 < 2; ++kc2) {
      if (kc2 == 0 || !diag || w >= 2) {
#pragma unroll
        for (int n = 0; n < 4; ++n) {
          const int row = n * 16 + fr;
          bf16x8 bv = *(const bf16x8*)&Vt[row * 64 + ((kc2 * 32 + fkg * 8) ^ ((row & 7) << 3))];
          ao[n] = __builtin_amdgcn_mfma_f32_16x16x32_bf16(pa[kc2], bv, ao[n], 0, 0, 0);
        }
      }
    }
    __syncthreads();
  }

  // ---- write O in [B][S][D] layout ----
  const int b = bh >> 4, h = bh & 15;
#pragma unroll
  for (int n = 0; n < 4; ++n)
#pragma unroll
    for (int r = 0; r < 4; ++r) {
      const int qg = q0 + fkg * 4 + r;
      const float ov = ao[n][r] / l_r[r];
      O[((size_t)(b * kS + qg) << 10) + h * 64 + n * 16 + fr] = (bf16)ov;
    }
}

// ---------------- launch ----------------
extern "C" void kernel_launch(void* const* d_in, const int* in_sizes, int n_in,
                              void* d_out, int out_size, void* d_ws, size_t ws_size,
                              hipStream_t stream) {
  const float* x  = (const float*)d_in[0];
  const float* wq = (const float*)d_in[1];
  const float* wk = (const float*)d_in[2];
  const float* wv = (const float*)d_in[3];
  const float* wo = (const float*)d_in[4];
  const int* pos  = (const int*)d_in[5];

  bf16* xb  = (bf16*)d_ws;                          // [8192][1024]
  bf16* wqb = xb  + (size_t)kM * kD;
  bf16* wkb = wqb + (size_t)kD * kD;
  bf16* wvb = wkb + (size_t)kD * kD;
  bf16* wob = wvb + (size_t)kD * kD;
  bf16* Qb  = wob + (size_t)kD * kD;                // [64][2048][64]
  bf16* Kbf = Qb  + (size_t)64 * kS * kDK;
  bf16* Vbf = Kbf + (size_t)64 * kS * kDK;
  bf16* Ob  = Vbf + (size_t)64 * kS * kDK;          // [8192][1024]

  {
    int n4 = kM * kD / 4;
    cvt_f32_bf16<<<(n4 + 255) / 256, 256, 0, stream>>>(x, xb, n4);
    n4 = kD * kD / 4;
    cvt_f32_bf16<<<(n4 + 255) / 256, 256, 0, stream>>>(wq, wqb, n4);
    cvt_f32_bf16<<<(n4 + 255) / 256, 256, 0, stream>>>(wk, wkb, n4);
    cvt_f32_bf16<<<(n4 + 255) / 256, 256, 0, stream>>>(wv, wvb, n4);
    cvt_f32_bf16<<<(n4 + 255) / 256, 256, 0, stream>>>(wo, wob, n4);
  }

  dim3 gg(kM / 128, kD / 128);   // 64 x 8
  gemm_bt<<<gg, 256, 0, stream>>>(xb, wqb, Qb, kD, 0);
  gemm_bt<<<gg, 256, 0, stream>>>(xb, wkb, Kbf, kD, 0);
  gemm_bt<<<gg, 256, 0, stream>>>(xb, wvb, Vbf, kD, 0);

  const int np = 64 * kS * 32;
  rope_kernel<<<(2 * np) / 256, 256, 0, stream>>>(Qb, Kbf, pos, np);

  dim3 ga(64, kS / 64);          // (bh, qtile)
  attn_fwd<<<ga, 256, 0, stream>>>(Qb, Kbf, Vbf, Ob);

  gemm_bt<<<gg, 256, 0, stream>>>(Ob, wob, d_out, kD, 1);
}

// Round 4
// 360.981 us; speedup vs baseline: 1.3647x; 1.0165x over previous
//
#include <hip/hip_runtime.h>
#include <hip/hip_bf16.h>
#include <stdint.h>
#include <math.h>

// Problem constants: B=4, S=2048, D=1024, H=16, DK=64
static constexpr int kS  = 2048;
static constexpr int kH  = 16;
static constexpr int kDK = 64;
static constexpr int kD  = 1024;
static constexpr int kB  = 4;
static constexpr int kM  = kB * kS;   // 8192 tokens

typedef __bf16 bf16;
typedef __attribute__((ext_vector_type(8))) __bf16 bf16x8;
typedef __attribute__((ext_vector_type(4))) __bf16 bf16x4;
typedef __attribute__((ext_vector_type(4))) float f32x4;

__device__ __forceinline__ void gload_lds16(const bf16* g, bf16* l) {
  __builtin_amdgcn_global_load_lds((__attribute__((address_space(1))) void*)(void*)g,
                                   (__attribute__((address_space(3))) void*)l, 16, 0, 0);
}

// ---------------- fp32 -> bf16 convert (vectorized) ----------------
__global__ void cvt_f32_bf16(const float* __restrict__ in, bf16* __restrict__ out, int n4) {
  int i = blockIdx.x * blockDim.x + threadIdx.x;
  if (i >= n4) return;
  float4 v = reinterpret_cast<const float4*>(in)[i];
  bf16x4 o;
  o[0] = (bf16)v.x; o[1] = (bf16)v.y; o[2] = (bf16)v.z; o[3] = (bf16)v.w;
  reinterpret_cast<bf16x4*>(out)[i] = o;
}

// ---------------- GEMM: out[m][n] = sum_k A[m][k] * W[n][k] ----------------
// Double-buffered LDS, single barrier per K-step (T3-minimum pipeline):
// issue next tile's global_load_lds BEFORE computing current tile; the
// __syncthreads at loop end (implicit vmcnt(0)+lgkmcnt(0) drain) both joins
// waves and guarantees next tile is resident.
__global__ __launch_bounds__(256) void gemm_bt(const bf16* __restrict__ A,
                                               const bf16* __restrict__ W,
                                               void* __restrict__ dst,
                                               int K, int mode) {
  __shared__ __align__(16) bf16 As[2][128 * 32];
  __shared__ __align__(16) bf16 Bs[2][128 * 32];

  const int tid = threadIdx.x;
  const int l   = tid & 63;
  const int w   = tid >> 6;                 // wave 0..3
  const int brow = blockIdx.x * 128;
  const int bcol = blockIdx.y * 128;
  const int wr = (w >> 1) * 64;
  const int wc = (w & 1) * 64;

  f32x4 acc[4][4] = {};

  const int lrow = l >> 2;                  // 0..15
  const int lcol = (l & 3) * 8;             // 0/8/16/24

  const int fr  = l & 15;
  const int fk  = (l >> 4) * 8;

  const int nk = K >> 5;

  // stage tile kt into buffer buf (4 gload_lds per thread)
#define STAGE(buf, kt)                                                        \
  {                                                                           \
    const int k0_ = (kt) << 5;                                                \
    _Pragma("unroll")                                                         \
    for (int c2 = 0; c2 < 2; ++c2) {                                          \
      const int c = w * 2 + c2;                                               \
      const int r = c * 16 + lrow;                                            \
      gload_lds16(A + (size_t)(brow + r) * K + k0_ + lcol, &As[buf][c * 512]);\
      gload_lds16(W + (size_t)(bcol + r) * K + k0_ + lcol, &Bs[buf][c * 512]);\
    }                                                                         \
  }

  STAGE(0, 0);
  __syncthreads();

  int cur = 0;
  for (int kt = 0; kt < nk; ++kt) {
    if (kt + 1 < nk) STAGE(cur ^ 1, kt + 1);   // prefetch next tile (in flight during compute)

    bf16x8 af[4], bfm[4];
#pragma unroll
    for (int m = 0; m < 4; ++m) af[m]  = *(const bf16x8*)&As[cur][(wr + m * 16 + fr) * 32 + fk];
#pragma unroll
    for (int n = 0; n < 4; ++n) bfm[n] = *(const bf16x8*)&Bs[cur][(wc + n * 16 + fr) * 32 + fk];
#pragma unroll
    for (int m = 0; m < 4; ++m)
#pragma unroll
      for (int n = 0; n < 4; ++n)
        acc[m][n] = __builtin_amdgcn_mfma_f32_16x16x32_bf16(af[m], bfm[n], acc[m][n], 0, 0, 0);

    __syncthreads();   // drains prefetch (vmcnt 0) + joins waves before buffer reuse
    cur ^= 1;
  }
#undef STAGE

  const int frow = (l >> 4) * 4;
  if (mode == 0) {
    bf16* out = (bf16*)dst;
#pragma unroll
    for (int m = 0; m < 4; ++m) {
#pragma unroll
      for (int n = 0; n < 4; ++n) {
        const int col = bcol + wc + n * 16 + fr;
        const int h = col >> 6, dk = col & 63;
#pragma unroll
        for (int r = 0; r < 4; ++r) {
          const int row = brow + wr + m * 16 + frow + r;
          const int b = row >> 11, s = row & (kS - 1);
          out[((((size_t)b * kH + h) * kS + s) << 6) + dk] = (bf16)acc[m][n][r];
        }
      }
    }
  } else {
    float* out = (float*)dst;
#pragma unroll
    for (int m = 0; m < 4; ++m) {
#pragma unroll
      for (int n = 0; n < 4; ++n) {
        const int col = bcol + wc + n * 16 + fr;
#pragma unroll
        for (int r = 0; r < 4; ++r) {
          const int row = brow + wr + m * 16 + frow + r;
          out[(size_t)row * kD + col] = acc[m][n][r];
        }
      }
    }
  }
}

// ---------------- RoPE (interleaved pairs), in-place on Q and K ----------------
__global__ void rope_kernel(bf16* __restrict__ Q, bf16* __restrict__ Kb,
                            const int* __restrict__ pos, int np) {
  int idx = blockIdx.x * blockDim.x + threadIdx.x;
  if (idx >= 2 * np) return;
  bf16* T = (idx < np) ? Q : Kb;
  int id = (idx < np) ? idx : idx - np;
  const int i = id & 31;
  const int s = (id >> 5) & (kS - 1);
  const float p = (float)pos[s];
  const float freq = __expf(-0.2878231366242557f * (float)i);
  const float f = p * freq;
  float sn, cs;
  sincosf(f, &sn, &cs);
  const size_t off = (size_t)id * 2;
  const float e = (float)T[off], o = (float)T[off + 1];
  T[off]     = (bf16)(e * cs - o * sn);
  T[off + 1] = (bf16)(o * cs + e * sn);
}

// ---------------- causal flash attention v2.1 ----------------
// Q,K,V: [BH][S][DK] bf16. O: [B][S][D] bf16.
// grid: (BH, S/64); block 256 = 4 waves; wave w owns 16 q-rows.
// KVBLK=64; K/Vt/P LDS XOR-swizzled. Base-2 online softmax (exp2).
__global__ __launch_bounds__(256) void attn_fwd(const bf16* __restrict__ Q,
                                                const bf16* __restrict__ Kb,
                                                const bf16* __restrict__ Vb,
                                                bf16* __restrict__ O) {
  const int bh = blockIdx.x;
  const int qt = (int)gridDim.y - 1 - (int)blockIdx.y;   // heavy blocks first
  const int tid = threadIdx.x;
  const int l = tid & 63;
  const int w = tid >> 6;

  __shared__ __align__(16) bf16 Ks[64 * 64];   // [kv][dk], swizzled
  __shared__ __align__(16) bf16 Vt[64 * 64];   // [dk][kv], swizzled
  __shared__ __align__(16) bf16 Pl[4][16 * 64];// per-wave [q][kv], swizzled

  const int q0 = qt * 64 + w * 16;
  const int fr  = l & 15;
  const int fkg = l >> 4;                      // 0..3
  const size_t base = (size_t)bh * kS * kDK;

  // scale folded with log2(e): softmax computed in base-2 domain
  const float SC2 = 0.125f * 1.4426950408889634f;

  bf16x8 aq[2];
#pragma unroll
  for (int kc = 0; kc < 2; ++kc)
    aq[kc] = *(const bf16x8*)&Q[base + (size_t)(q0 + fr) * kDK + kc * 32 + fkg * 8];

  f32x4 ao[4] = {};
  float m_r[4], l_r[4];
#pragma unroll
  for (int r = 0; r < 4; ++r) { m_r[r] = -1e30f; l_r[r] = 0.f; }

  const int nt = qt + 1;

  const int krow = tid >> 3;                   // 0..31 (+32 second pass)
  const int kcol = (tid & 7) * 8;
  const int dk0  = w * 16;                     // V: wave owns 16 dk cols; lane = kv

  bf16x8 kreg0, kreg1, vreg0, vreg1;
  {
    const size_t kb0 = base + (size_t)krow * kDK + kcol;
    kreg0 = *(const bf16x8*)&Kb[kb0];
    kreg1 = *(const bf16x8*)&Kb[kb0 + 32 * kDK];
    const size_t vb0 = base + (size_t)l * kDK + dk0;
    vreg0 = *(const bf16x8*)&Vb[vb0];
    vreg1 = *(const bf16x8*)&Vb[vb0 + 8];
  }

  for (int j = 0; j < nt; ++j) {
    {
      const int r0 = krow, r1 = krow + 32;
      *(bf16x8*)&Ks[r0 * 64 + (kcol ^ ((r0 & 7) << 3))] = kreg0;
      *(bf16x8*)&Ks[r1 * 64 + (kcol ^ ((r1 & 7) << 3))] = kreg1;
#pragma unroll
      for (int e = 0; e < 8; ++e) {
        const int d0 = dk0 + e, d1 = dk0 + 8 + e;
        Vt[d0 * 64 + (l ^ ((d0 & 7) << 3))] = vreg0[e];
        Vt[d1 * 64 + (l ^ ((d1 & 7) << 3))] = vreg1[e];
      }
    }
    __syncthreads();

    if (j + 1 < nt) {
      const size_t kb0 = base + (size_t)((j + 1) * 64 + krow) * kDK + kcol;
      kreg0 = *(const bf16x8*)&Kb[kb0];
      kreg1 = *(const bf16x8*)&Kb[kb0 + 32 * kDK];
      const size_t vb0 = base + (size_t)((j + 1) * 64 + l) * kDK + dk0;
      vreg0 = *(const bf16x8*)&Vb[vb0];
      vreg1 = *(const bf16x8*)&Vb[vb0 + 8];
    }

    const bool diag = (j == nt - 1);

    // ---- scores: 16 x 64 ----
    f32x4 sc[4] = {};
#pragma unroll
    for (int nf = 0; nf < 4; ++nf) {
      if (!diag || nf <= w) {
#pragma unroll
        for (int kc = 0; kc < 2; ++kc) {
          const int row = nf * 16 + fr;
          bf16x8 bk = *(const bf16x8*)&Ks[row * 64 + ((kc * 32 + fkg * 8) ^ ((row & 7) << 3))];
          sc[nf] = __builtin_amdgcn_mfma_f32_16x16x32_bf16(aq[kc], bk, sc[nf], 0, 0, 0);
        }
      }
    }

    // ---- online softmax, base-2 ----
    float p[4][4];
#pragma unroll
    for (int r = 0; r < 4; ++r) {
      const int qloc = w * 16 + fkg * 4 + r;
      float s[4];
#pragma unroll
      for (int nf = 0; nf < 4; ++nf) {
        s[nf] = sc[nf][r] * SC2;
        if (diag && (nf * 16 + fr) > qloc) s[nf] = -INFINITY;
      }
      float mx = fmaxf(fmaxf(s[0], s[1]), fmaxf(s[2], s[3]));
#pragma unroll
      for (int d = 1; d < 16; d <<= 1) mx = fmaxf(mx, __shfl_xor(mx, d));
      const float mnew = fmaxf(m_r[r], mx);
      const float sf = exp2f(m_r[r] - mnew);
      float rs = 0.f;
#pragma unroll
      for (int nf = 0; nf < 4; ++nf) { p[nf][r] = exp2f(s[nf] - mnew); rs += p[nf][r]; }
#pragma unroll
      for (int d = 1; d < 16; d <<= 1) rs += __shfl_xor(rs, d);
      l_r[r] = l_r[r] * sf + rs;
      m_r[r] = mnew;
#pragma unroll
      for (int n = 0; n < 4; ++n) ao[n][r] *= sf;
    }

    // ---- P -> per-wave LDS (swizzled), reload as A fragments ----
#pragma unroll
    for (int r = 0; r < 4; ++r) {
      const int qrow = fkg * 4 + r;
      const int sw = (qrow & 7) << 3;
#pragma unroll
      for (int nf = 0; nf < 4; ++nf)
        Pl[w][qrow * 64 + ((nf * 16 + fr) ^ sw)] = (bf16)p[nf][r];
    }
    bf16x8 pa[2];
#pragma unroll
    for (int kc2 = 0; kc2 < 2; ++kc2)
      pa[kc2] = *(const bf16x8*)&Pl[w][fr * 64 + ((kc2 * 32 + fkg * 8) ^ ((fr & 7) << 3))];

    // ---- PV ----
#pragma unroll
    for (int kc2 = 0; kc2 < 2; ++kc2) {
      if (kc2 == 0 || !diag || w >= 2) {
#pragma unroll
        for (int n = 0; n < 4; ++n) {
          const int row = n * 16 + fr;
          bf16x8 bv = *(const bf16x8*)&Vt[row * 64 + ((kc2 * 32 + fkg * 8) ^ ((row & 7) << 3))];
          ao[n] = __builtin_amdgcn_mfma_f32_16x16x32_bf16(pa[kc2], bv, ao[n], 0, 0, 0);
        }
      }
    }
    __syncthreads();
  }

  // ---- write O ----
  const int b = bh >> 4, h = bh & 15;
#pragma unroll
  for (int n = 0; n < 4; ++n)
#pragma unroll
    for (int r = 0; r < 4; ++r) {
      const int qg = q0 + fkg * 4 + r;
      const float ov = ao[n][r] / l_r[r];
      O[((size_t)(b * kS + qg) << 10) + h * 64 + n * 16 + fr] = (bf16)ov;
    }
}

// ---------------- launch ----------------
extern "C" void kernel_launch(void* const* d_in, const int* in_sizes, int n_in,
                              void* d_out, int out_size, void* d_ws, size_t ws_size,
                              hipStream_t stream) {
  const float* x  = (const float*)d_in[0];
  const float* wq = (const float*)d_in[1];
  const float* wk = (const float*)d_in[2];
  const float* wv = (const float*)d_in[3];
  const float* wo = (const float*)d_in[4];
  const int* pos  = (const int*)d_in[5];

  bf16* xb  = (bf16*)d_ws;                          // [8192][1024]
  bf16* wqb = xb  + (size_t)kM * kD;
  bf16* wkb = wqb + (size_t)kD * kD;
  bf16* wvb = wkb + (size_t)kD * kD;
  bf16* wob = wvb + (size_t)kD * kD;
  bf16* Qb  = wob + (size_t)kD * kD;                // [64][2048][64]
  bf16* Kbf = Qb  + (size_t)64 * kS * kDK;
  bf16* Vbf = Kbf + (size_t)64 * kS * kDK;
  bf16* Ob  = Vbf + (size_t)64 * kS * kDK;          // [8192][1024]

  {
    int n4 = kM * kD / 4;
    cvt_f32_bf16<<<(n4 + 255) / 256, 256, 0, stream>>>(x, xb, n4);
    n4 = kD * kD / 4;
    cvt_f32_bf16<<<(n4 + 255) / 256, 256, 0, stream>>>(wq, wqb, n4);
    cvt_f32_bf16<<<(n4 + 255) / 256, 256, 0, stream>>>(wk, wkb, n4);
    cvt_f32_bf16<<<(n4 + 255) / 256, 256, 0, stream>>>(wv, wvb, n4);
    cvt_f32_bf16<<<(n4 + 255) / 256, 256, 0, stream>>>(wo, wob, n4);
  }

  dim3 gg(kM / 128, kD / 128);   // 64 x 8
  gemm_bt<<<gg, 256, 0, stream>>>(xb, wqb, Qb, kD, 0);
  gemm_bt<<<gg, 256, 0, stream>>>(xb, wkb, Kbf, kD, 0);
  gemm_bt<<<gg, 256, 0, stream>>>(xb, wvb, Vbf, kD, 0);

  const int np = 64 * kS * 32;
  rope_kernel<<<(2 * np) / 256, 256, 0, stream>>>(Qb, Kbf, pos, np);

  dim3 ga(64, kS / 64);          // (bh, qtile)
  attn_fwd<<<ga, 256, 0, stream>>>(Qb, Kbf, Vbf, Ob);

  gemm_bt<<<gg, 256, 0, stream>>>(Ob, wob, d_out, kD, 1);
}

// Round 5
// 315.118 us; speedup vs baseline: 1.5633x; 1.1455x over previous
//
#include <hip/hip_runtime.h>
#include <hip/hip_bf16.h>
#include <stdint.h>
#include <math.h>

// Problem constants: B=4, S=2048, D=1024, H=16, DK=64
static constexpr int kS  = 2048;
static constexpr int kH  = 16;
static constexpr int kDK = 64;
static constexpr int kD  = 1024;
static constexpr int kB  = 4;
static constexpr int kM  = kB * kS;   // 8192 tokens

typedef __bf16 bf16;
typedef __attribute__((ext_vector_type(8))) __bf16 bf16x8;
typedef __attribute__((ext_vector_type(4))) __bf16 bf16x4;
typedef __attribute__((ext_vector_type(4))) float f32x4;

__device__ __forceinline__ void gload_lds16(const bf16* g, bf16* l) {
  __builtin_amdgcn_global_load_lds((__attribute__((address_space(1))) void*)(void*)g,
                                   (__attribute__((address_space(3))) void*)l, 16, 0, 0);
}

// ---------------- fp32 -> bf16 convert (vectorized) ----------------
__global__ void cvt_f32_bf16(const float* __restrict__ in, bf16* __restrict__ out, int n4) {
  int i = blockIdx.x * blockDim.x + threadIdx.x;
  if (i >= n4) return;
  float4 v = reinterpret_cast<const float4*>(in)[i];
  bf16x4 o;
  o[0] = (bf16)v.x; o[1] = (bf16)v.y; o[2] = (bf16)v.z; o[3] = (bf16)v.w;
  reinterpret_cast<bf16x4*>(out)[i] = o;
}

// ---------------- GEMM body: out[m][n] = sum_k A[m][k] * W[n][k] ----------------
// BM x 128 tile, BK=32, double-buffered LDS, prefetch-before-compute.
// mode 0: bf16 permuted [B][H][S][DK]; mode 1: fp32 linear [M][kD].
template<int BM>
__device__ __forceinline__ void gemm_body(const bf16* __restrict__ A,
                                          const bf16* __restrict__ W,
                                          void* __restrict__ dst,
                                          int K, int mode, int brow, int bcol) {
  constexpr int MF  = BM / 32;        // m-frags per wave (wave covers BM/2 rows)
  constexpr int ACH = BM / 64;        // A 16-row chunks per wave

  __shared__ __align__(16) bf16 As[2][BM * 32];
  __shared__ __align__(16) bf16 Bs[2][128 * 32];

  const int tid = threadIdx.x;
  const int l   = tid & 63;
  const int w   = tid >> 6;                 // wave 0..3
  const int wr = (w >> 1) * (BM / 2);
  const int wc = (w & 1) * 64;

  f32x4 acc[MF][4] = {};

  const int lrow = l >> 2;                  // 0..15
  const int lcol = (l & 3) * 8;             // 0/8/16/24
  const int fr  = l & 15;
  const int fk  = (l >> 4) * 8;

  const int nk = K >> 5;

  auto STAGE = [&](int buf, int kt) {
    const int k0 = kt << 5;
#pragma unroll
    for (int c2 = 0; c2 < ACH; ++c2) {
      const int c = w * ACH + c2;
      gload_lds16(A + (size_t)(brow + c * 16 + lrow) * K + k0 + lcol, &As[buf][c * 512]);
    }
#pragma unroll
    for (int c2 = 0; c2 < 2; ++c2) {
      const int c = w * 2 + c2;
      gload_lds16(W + (size_t)(bcol + c * 16 + lrow) * K + k0 + lcol, &Bs[buf][c * 512]);
    }
  };

  STAGE(0, 0);
  __syncthreads();

  int cur = 0;
  for (int kt = 0; kt < nk; ++kt) {
    if (kt + 1 < nk) STAGE(cur ^ 1, kt + 1);   // in flight during compute

    bf16x8 af[MF], bfm[4];
#pragma unroll
    for (int m = 0; m < MF; ++m) af[m]  = *(const bf16x8*)&As[cur][(wr + m * 16 + fr) * 32 + fk];
#pragma unroll
    for (int n = 0; n < 4; ++n)  bfm[n] = *(const bf16x8*)&Bs[cur][(wc + n * 16 + fr) * 32 + fk];
#pragma unroll
    for (int m = 0; m < MF; ++m)
#pragma unroll
      for (int n = 0; n < 4; ++n)
        acc[m][n] = __builtin_amdgcn_mfma_f32_16x16x32_bf16(af[m], bfm[n], acc[m][n], 0, 0, 0);

    __syncthreads();   // drains prefetch + joins waves before buffer reuse
    cur ^= 1;
  }

  const int frow = (l >> 4) * 4;
  if (mode == 0) {
    bf16* out = (bf16*)dst;
#pragma unroll
    for (int m = 0; m < MF; ++m) {
#pragma unroll
      for (int n = 0; n < 4; ++n) {
        const int col = bcol + wc + n * 16 + fr;
        const int h = col >> 6, dk = col & 63;
#pragma unroll
        for (int r = 0; r < 4; ++r) {
          const int row = brow + wr + m * 16 + frow + r;
          const int b = row >> 11, s = row & (kS - 1);
          out[((((size_t)b * kH + h) * kS + s) << 6) + dk] = (bf16)acc[m][n][r];
        }
      }
    }
  } else {
    float* out = (float*)dst;
#pragma unroll
    for (int m = 0; m < MF; ++m) {
#pragma unroll
      for (int n = 0; n < 4; ++n) {
        const int col = bcol + wc + n * 16 + fr;
#pragma unroll
        for (int r = 0; r < 4; ++r) {
          const int row = brow + wr + m * 16 + frow + r;
          out[(size_t)row * kD + col] = acc[m][n][r];
        }
      }
    }
  }
}

template<int BM>
__global__ __launch_bounds__(256) void gemm_k(const bf16* __restrict__ A,
                                              const bf16* __restrict__ W,
                                              void* __restrict__ dst, int K, int mode) {
  gemm_body<BM>(A, W, dst, K, mode, blockIdx.x * BM, blockIdx.y * 128);
}

// Fused QKV: grid (kM/64, 24); by>>3 selects Q/K/V, by&7 the 128-col block.
__global__ __launch_bounds__(256) void gemm_qkv(const bf16* __restrict__ A,
                                                const bf16* __restrict__ wq,
                                                const bf16* __restrict__ wk,
                                                const bf16* __restrict__ wv,
                                                bf16* __restrict__ Qb,
                                                bf16* __restrict__ Kb,
                                                bf16* __restrict__ Vb, int K) {
  const int by = blockIdx.y;
  const int sel = by >> 3;
  const bf16* W = (sel == 0) ? wq : (sel == 1) ? wk : wv;
  bf16* dst     = (sel == 0) ? Qb : (sel == 1) ? Kb : Vb;
  gemm_body<64>(A, W, dst, K, 0, blockIdx.x * 64, (by & 7) * 128);
}

// ---------------- RoPE (interleaved pairs), in-place on Q and K ----------------
__global__ void rope_kernel(bf16* __restrict__ Q, bf16* __restrict__ Kb,
                            const int* __restrict__ pos, int np) {
  int idx = blockIdx.x * blockDim.x + threadIdx.x;
  if (idx >= 2 * np) return;
  bf16* T = (idx < np) ? Q : Kb;
  int id = (idx < np) ? idx : idx - np;
  const int i = id & 31;
  const int s = (id >> 5) & (kS - 1);
  const float p = (float)pos[s];
  const float freq = __expf(-0.2878231366242557f * (float)i);
  const float f = p * freq;
  float sn, cs;
  sincosf(f, &sn, &cs);
  const size_t off = (size_t)id * 2;
  const float e = (float)T[off], o = (float)T[off + 1];
  T[off]     = (bf16)(e * cs - o * sn);
  T[off + 1] = (bf16)(o * cs + e * sn);
}

// ---------------- causal flash attention v3: swapped QK^T ----------------
// sc = mfma(Kfrag, Qfrag): C col(=lane&15) = q, row = k. Each lane holds 16
// scores for ONE q-row -> softmax = in-lane chain + shfl_xor(16,32).
// exp via raw v_exp_f32 (base-2, scale folded with log2e).
__global__ __launch_bounds__(256) void attn_fwd(const bf16* __restrict__ Q,
                                                const bf16* __restrict__ Kb,
                                                const bf16* __restrict__ Vb,
                                                bf16* __restrict__ O) {
  const int bh = blockIdx.x;
  const int qt = (int)gridDim.y - 1 - (int)blockIdx.y;   // heavy blocks first
  const int tid = threadIdx.x;
  const int l = tid & 63;
  const int w = tid >> 6;

  __shared__ __align__(16) bf16 Ks[64 * 64];   // [kv][dk], swizzled
  __shared__ __align__(16) bf16 Vt[64 * 64];   // [dk][kv], swizzled
  __shared__ __align__(16) bf16 Pl[4][16 * 64];// per-wave [q][kv], swizzled

  const int q0 = qt * 64 + w * 16;
  const int fr  = l & 15;
  const int fkg = l >> 4;                      // 0..3
  const int fkg4 = fkg << 2;
  const size_t base = (size_t)bh * kS * kDK;

  const float SC2 = 0.125f * 1.4426950408889634f;  // 1/sqrt(DK) * log2(e)

  bf16x8 aq[2];
#pragma unroll
  for (int kc = 0; kc < 2; ++kc)
    aq[kc] = *(const bf16x8*)&Q[base + (size_t)(q0 + fr) * kDK + kc * 32 + fkg * 8];

  f32x4 ao[4] = {};
  float m_r = -1e30f, l_r = 0.f;               // state for q = q0 + fr (replicated x4 fkg)

  const int nt = qt + 1;

  const int krow = tid >> 3;                   // 0..31 (+32 second pass)
  const int kcol = (tid & 7) * 8;
  const int dk0  = w * 16;                     // V: wave owns 16 dk cols; lane = kv

  bf16x8 kreg0, kreg1, vreg0, vreg1;
  {
    const size_t kb0 = base + (size_t)krow * kDK + kcol;
    kreg0 = *(const bf16x8*)&Kb[kb0];
    kreg1 = *(const bf16x8*)&Kb[kb0 + 32 * kDK];
    const size_t vb0 = base + (size_t)l * kDK + dk0;
    vreg0 = *(const bf16x8*)&Vb[vb0];
    vreg1 = *(const bf16x8*)&Vb[vb0 + 8];
  }

  for (int j = 0; j < nt; ++j) {
    {
      const int r0 = krow, r1 = krow + 32;
      *(bf16x8*)&Ks[r0 * 64 + (kcol ^ ((r0 & 7) << 3))] = kreg0;
      *(bf16x8*)&Ks[r1 * 64 + (kcol ^ ((r1 & 7) << 3))] = kreg1;
#pragma unroll
      for (int e = 0; e < 8; ++e) {
        const int d0 = dk0 + e, d1 = dk0 + 8 + e;
        Vt[d0 * 64 + (l ^ ((d0 & 7) << 3))] = vreg0[e];
        Vt[d1 * 64 + (l ^ ((d1 & 7) << 3))] = vreg1[e];
      }
    }
    __syncthreads();

    if (j + 1 < nt) {
      const size_t kb0 = base + (size_t)((j + 1) * 64 + krow) * kDK + kcol;
      kreg0 = *(const bf16x8*)&Kb[kb0];
      kreg1 = *(const bf16x8*)&Kb[kb0 + 32 * kDK];
      const size_t vb0 = base + (size_t)((j + 1) * 64 + l) * kDK + dk0;
      vreg0 = *(const bf16x8*)&Vb[vb0];
      vreg1 = *(const bf16x8*)&Vb[vb0 + 8];
    }

    const bool diag = (j == nt - 1);

    // ---- scores (swapped): sc[nf] row = k = nf*16+fkg*4+r, col = q = fr ----
    f32x4 sc[4] = {};
#pragma unroll
    for (int nf = 0; nf < 4; ++nf) {
      if (!diag || nf <= w) {
#pragma unroll
        for (int kc = 0; kc < 2; ++kc) {
          const int row = nf * 16 + fr;
          bf16x8 bk = *(const bf16x8*)&Ks[row * 64 + ((kc * 32 + fkg * 8) ^ ((row & 7) << 3))];
          sc[nf] = __builtin_amdgcn_mfma_f32_16x16x32_bf16(bk, aq[kc], sc[nf], 0, 0, 0);
        }
      }
    }

    // ---- online softmax, base-2, in-lane + 2-shfl reduces ----
    const int qloc = w * 16 + fr;
    float p[4][4];
    float mx = -INFINITY;
#pragma unroll
    for (int nf = 0; nf < 4; ++nf)
#pragma unroll
      for (int r = 0; r < 4; ++r) {
        float s = sc[nf][r] * SC2;
        if (diag && (nf * 16 + fkg4 + r) > qloc) s = -INFINITY;
        p[nf][r] = s;
        mx = fmaxf(mx, s);
      }
    mx = fmaxf(mx, __shfl_xor(mx, 16));
    mx = fmaxf(mx, __shfl_xor(mx, 32));
    const float mnew = fmaxf(m_r, mx);
    const float sf = __builtin_amdgcn_exp2f(m_r - mnew);
    float rs = 0.f;
#pragma unroll
    for (int nf = 0; nf < 4; ++nf)
#pragma unroll
      for (int r = 0; r < 4; ++r) {
        p[nf][r] = __builtin_amdgcn_exp2f(p[nf][r] - mnew);
        rs += p[nf][r];
      }
    rs += __shfl_xor(rs, 16);
    rs += __shfl_xor(rs, 32);
    l_r = l_r * sf + rs;
    m_r = mnew;

    // broadcast sf to the ao-row owners: ao row q' = fkg*4 + r lives at lane fr' = q'
#pragma unroll
    for (int r = 0; r < 4; ++r) {
      const float sfq = __shfl(sf, (l & 48) + fkg4 + r);
#pragma unroll
      for (int n = 0; n < 4; ++n) ao[n][r] *= sfq;
    }

    // ---- P -> per-wave LDS: lane holds P[k = nf*16+fkg4+r][q = fr] ----
#pragma unroll
    for (int nf = 0; nf < 4; ++nf) {
      bf16x4 p4;
#pragma unroll
      for (int r = 0; r < 4; ++r) p4[r] = (bf16)p[nf][r];
      *(bf16x4*)&Pl[w][fr * 64 + ((nf * 16 + fkg4) ^ ((fr & 7) << 3))] = p4;
    }
    bf16x8 pa[2];
#pragma unroll
    for (int kc2 = 0; kc2 < 2; ++kc2)
      pa[kc2] = *(const bf16x8*)&Pl[w][fr * 64 + ((kc2 * 32 + fkg * 8) ^ ((fr & 7) << 3))];

    // ---- PV ----
#pragma unroll
    for (int kc2 = 0; kc2 < 2; ++kc2) {
      if (kc2 == 0 || !diag || w >= 2) {
#pragma unroll
        for (int n = 0; n < 4; ++n) {
          const int row = n * 16 + fr;
          bf16x8 bv = *(const bf16x8*)&Vt[row * 64 + ((kc2 * 32 + fkg * 8) ^ ((row & 7) << 3))];
          ao[n] = __builtin_amdgcn_mfma_f32_16x16x32_bf16(pa[kc2], bv, ao[n], 0, 0, 0);
        }
      }
    }
    __syncthreads();
  }

  // ---- write O: ao[n][r] is O[q = q0 + fkg4 + r][dk = n*16 + fr] ----
  const int b = bh >> 4, h = bh & 15;
  float lq[4];
#pragma unroll
  for (int r = 0; r < 4; ++r) lq[r] = __shfl(l_r, (l & 48) + fkg4 + r);
#pragma unroll
  for (int n = 0; n < 4; ++n)
#pragma unroll
    for (int r = 0; r < 4; ++r) {
      const int qg = q0 + fkg4 + r;
      const float ov = ao[n][r] / lq[r];
      O[((size_t)(b * kS + qg) << 10) + h * 64 + n * 16 + fr] = (bf16)ov;
    }
}

// ---------------- launch ----------------
extern "C" void kernel_launch(void* const* d_in, const int* in_sizes, int n_in,
                              void* d_out, int out_size, void* d_ws, size_t ws_size,
                              hipStream_t stream) {
  const float* x  = (const float*)d_in[0];
  const float* wq = (const float*)d_in[1];
  const float* wk = (const float*)d_in[2];
  const float* wv = (const float*)d_in[3];
  const float* wo = (const float*)d_in[4];
  const int* pos  = (const int*)d_in[5];

  bf16* xb  = (bf16*)d_ws;                          // [8192][1024]
  bf16* wqb = xb  + (size_t)kM * kD;
  bf16* wkb = wqb + (size_t)kD * kD;
  bf16* wvb = wkb + (size_t)kD * kD;
  bf16* wob = wvb + (size_t)kD * kD;
  bf16* Qb  = wob + (size_t)kD * kD;                // [64][2048][64]
  bf16* Kbf = Qb  + (size_t)64 * kS * kDK;
  bf16* Vbf = Kbf + (size_t)64 * kS * kDK;
  bf16* Ob  = Vbf + (size_t)64 * kS * kDK;          // [8192][1024]

  {
    int n4 = kM * kD / 4;
    cvt_f32_bf16<<<(n4 + 255) / 256, 256, 0, stream>>>(x, xb, n4);
    n4 = kD * kD / 4;
    cvt_f32_bf16<<<(n4 + 255) / 256, 256, 0, stream>>>(wq, wqb, n4);
    cvt_f32_bf16<<<(n4 + 255) / 256, 256, 0, stream>>>(wk, wkb, n4);
    cvt_f32_bf16<<<(n4 + 255) / 256, 256, 0, stream>>>(wv, wvb, n4);
    cvt_f32_bf16<<<(n4 + 255) / 256, 256, 0, stream>>>(wo, wob, n4);
  }

  // fused QKV: 3072 blocks (~6 resident blocks/CU)
  gemm_qkv<<<dim3(kM / 64, 24), 256, 0, stream>>>(xb, wqb, wkb, wvb, Qb, Kbf, Vbf, kD);

  const int np = 64 * kS * 32;
  rope_kernel<<<(2 * np) / 256, 256, 0, stream>>>(Qb, Kbf, pos, np);

  dim3 ga(64, kS / 64);          // (bh, qtile)
  attn_fwd<<<ga, 256, 0, stream>>>(Qb, Kbf, Vbf, Ob);

  // WO: 64-row tiles -> 1024 blocks (4/CU)
  gemm_k<64><<<dim3(kM / 64, kD / 128), 256, 0, stream>>>(Ob, wob, d_out, kD, 1);
}

// Round 7
// 278.628 us; speedup vs baseline: 1.7680x; 1.1310x over previous
//
#include <hip/hip_runtime.h>
#include <hip/hip_bf16.h>
#include <stdint.h>
#include <math.h>

// Problem constants: B=4, S=2048, D=1024, H=16, DK=64
static constexpr int kS  = 2048;
static constexpr int kH  = 16;
static constexpr int kDK = 64;
static constexpr int kD  = 1024;
static constexpr int kB  = 4;
static constexpr int kM  = kB * kS;   // 8192 tokens

typedef __bf16 bf16;
typedef __attribute__((ext_vector_type(8))) __bf16 bf16x8;
typedef __attribute__((ext_vector_type(4))) __bf16 bf16x4;
typedef __attribute__((ext_vector_type(4))) float f32x4;

__device__ __forceinline__ void gload_lds16(const bf16* g, bf16* l) {
  __builtin_amdgcn_global_load_lds((__attribute__((address_space(1))) void*)(void*)g,
                                   (__attribute__((address_space(3))) void*)l, 16, 0, 0);
}

// ---------------- fp32 -> bf16 converts ----------------
__global__ void cvt_f32_bf16(const float* __restrict__ in, bf16* __restrict__ out, int n4) {
  int i = blockIdx.x * blockDim.x + threadIdx.x;
  if (i >= n4) return;
  float4 v = reinterpret_cast<const float4*>(in)[i];
  bf16x4 o;
  o[0] = (bf16)v.x; o[1] = (bf16)v.y; o[2] = (bf16)v.z; o[3] = (bf16)v.w;
  reinterpret_cast<bf16x4*>(out)[i] = o;
}

// 4 weight matrices in one dispatch (blockIdx.y selects)
__global__ void cvt_w4(const float* __restrict__ w0, const float* __restrict__ w1,
                       const float* __restrict__ w2, const float* __restrict__ w3,
                       bf16* __restrict__ o0, bf16* __restrict__ o1,
                       bf16* __restrict__ o2, bf16* __restrict__ o3, int n4) {
  int i = blockIdx.x * blockDim.x + threadIdx.x;
  if (i >= n4) return;
  const int sel = blockIdx.y;
  const float* in = (sel == 0) ? w0 : (sel == 1) ? w1 : (sel == 2) ? w2 : w3;
  bf16* out      = (sel == 0) ? o0 : (sel == 1) ? o1 : (sel == 2) ? o2 : o3;
  float4 v = reinterpret_cast<const float4*>(in)[i];
  bf16x4 o;
  o[0] = (bf16)v.x; o[1] = (bf16)v.y; o[2] = (bf16)v.z; o[3] = (bf16)v.w;
  reinterpret_cast<bf16x4*>(out)[i] = o;
}

// ---------------- GEMM body: out[m][n] = sum_k A[m][k] * W[n][k] ----------------
// BM x 128 tile, BK=64 staged as two independent BK=32 halves (no swizzle
// needed: 64B row stride = 2-way bank alias = free). 32 MFMA/wave between
// barriers -> prefetch drain amortized 2x vs BK=32.
template<int BM>
__device__ __forceinline__ void gemm_body(const bf16* __restrict__ A,
                                          const bf16* __restrict__ W,
                                          void* __restrict__ dst,
                                          int K, int mode, int brow, int bcol) {
  constexpr int MF  = BM / 32;        // m-frags per wave
  constexpr int ACH = BM / 64;        // A 16-row chunks per wave per half

  __shared__ __align__(16) bf16 As[2][2][BM * 32];   // [dbuf][half][...]
  __shared__ __align__(16) bf16 Bs[2][2][128 * 32];

  const int tid = threadIdx.x;
  const int l   = tid & 63;
  const int w   = tid >> 6;                 // wave 0..3
  const int wr = (w >> 1) * (BM / 2);
  const int wc = (w & 1) * 64;

  f32x4 acc[MF][4] = {};

  const int lrow = l >> 2;                  // 0..15
  const int lcol = (l & 3) * 8;             // 0/8/16/24
  const int fr  = l & 15;
  const int fk  = (l >> 4) * 8;

  const int nk = K >> 6;                    // 64-wide K steps

  auto STAGE = [&](int buf, int kt) {
#pragma unroll
    for (int h = 0; h < 2; ++h) {
      const int k0 = (kt << 6) + h * 32;
#pragma unroll
      for (int c2 = 0; c2 < ACH; ++c2) {
        const int c = w * ACH + c2;
        gload_lds16(A + (size_t)(brow + c * 16 + lrow) * K + k0 + lcol, &As[buf][h][c * 512]);
      }
#pragma unroll
      for (int c2 = 0; c2 < 2; ++c2) {
        const int c = w * 2 + c2;
        gload_lds16(W + (size_t)(bcol + c * 16 + lrow) * K + k0 + lcol, &Bs[buf][h][c * 512]);
      }
    }
  };

  STAGE(0, 0);
  __syncthreads();

  int cur = 0;
  for (int kt = 0; kt < nk; ++kt) {
    if (kt + 1 < nk) STAGE(cur ^ 1, kt + 1);   // in flight during compute

#pragma unroll
    for (int h = 0; h < 2; ++h) {
      bf16x8 af[MF], bfm[4];
#pragma unroll
      for (int m = 0; m < MF; ++m) af[m]  = *(const bf16x8*)&As[cur][h][(wr + m * 16 + fr) * 32 + fk];
#pragma unroll
      for (int n = 0; n < 4; ++n)  bfm[n] = *(const bf16x8*)&Bs[cur][h][(wc + n * 16 + fr) * 32 + fk];
#pragma unroll
      for (int m = 0; m < MF; ++m)
#pragma unroll
        for (int n = 0; n < 4; ++n)
          acc[m][n] = __builtin_amdgcn_mfma_f32_16x16x32_bf16(af[m], bfm[n], acc[m][n], 0, 0, 0);
    }

    __syncthreads();   // drains prefetch + joins waves before buffer reuse
    cur ^= 1;
  }

  const int frow = (l >> 4) * 4;
  if (mode == 0) {
    bf16* out = (bf16*)dst;
#pragma unroll
    for (int m = 0; m < MF; ++m) {
#pragma unroll
      for (int n = 0; n < 4; ++n) {
        const int col = bcol + wc + n * 16 + fr;
        const int h = col >> 6, dk = col & 63;
#pragma unroll
        for (int r = 0; r < 4; ++r) {
          const int row = brow + wr + m * 16 + frow + r;
          const int b = row >> 11, s = row & (kS - 1);
          out[((((size_t)b * kH + h) * kS + s) << 6) + dk] = (bf16)acc[m][n][r];
        }
      }
    }
  } else {
    float* out = (float*)dst;
#pragma unroll
    for (int m = 0; m < MF; ++m) {
#pragma unroll
      for (int n = 0; n < 4; ++n) {
        const int col = bcol + wc + n * 16 + fr;
#pragma unroll
        for (int r = 0; r < 4; ++r) {
          const int row = brow + wr + m * 16 + frow + r;
          out[(size_t)row * kD + col] = acc[m][n][r];
        }
      }
    }
  }
}

template<int BM>
__global__ __launch_bounds__(256) void gemm_k(const bf16* __restrict__ A,
                                              const bf16* __restrict__ W,
                                              void* __restrict__ dst, int K, int mode) {
  gemm_body<BM>(A, W, dst, K, mode, blockIdx.x * BM, blockIdx.y * 128);
}

// Fused QKV: grid (kM/128, 24); by>>3 selects Q/K/V, by&7 the 128-col block.
__global__ __launch_bounds__(256) void gemm_qkv(const bf16* __restrict__ A,
                                                const bf16* __restrict__ wq,
                                                const bf16* __restrict__ wk,
                                                const bf16* __restrict__ wv,
                                                bf16* __restrict__ Qb,
                                                bf16* __restrict__ Kb,
                                                bf16* __restrict__ Vb, int K) {
  const int by = blockIdx.y;
  const int sel = by >> 3;
  const bf16* W = (sel == 0) ? wq : (sel == 1) ? wk : wv;
  bf16* dst     = (sel == 0) ? Qb : (sel == 1) ? Kb : Vb;
  gemm_body<128>(A, W, dst, K, 0, blockIdx.x * 128, (by & 7) * 128);
}

// ---------------- RoPE, in-place; Q additionally pre-scaled by 1/8*log2e ----------------
// (folds the softmax scale into Q with ZERO extra rounding: same single bf16 cast)
__global__ void rope_kernel(bf16* __restrict__ Q, bf16* __restrict__ Kb,
                            const int* __restrict__ pos, int np) {
  int idx = blockIdx.x * blockDim.x + threadIdx.x;
  if (idx >= 2 * np) return;
  const bool isQ = (idx < np);
  bf16* T = isQ ? Q : Kb;
  int id = isQ ? idx : idx - np;
  const int i = id & 31;
  const int s = (id >> 5) & (kS - 1);
  const float p = (float)pos[s];
  const float freq = __expf(-0.2878231366242557f * (float)i);
  const float f = p * freq;
  float sn, cs;
  sincosf(f, &sn, &cs);
  const float sc = isQ ? (0.125f * 1.4426950408889634f) : 1.0f;
  const size_t off = (size_t)id * 2;
  const float e = (float)T[off], o = (float)T[off + 1];
  T[off]     = (bf16)((e * cs - o * sn) * sc);
  T[off + 1] = (bf16)((o * cs + e * sn) * sc);
}

// ---------------- causal flash attention v4 ----------------
// Swapped QK^T (lane = q-row), scale pre-folded into Q, defer-max rescale.
__global__ __launch_bounds__(256) void attn_fwd(const bf16* __restrict__ Q,
                                                const bf16* __restrict__ Kb,
                                                const bf16* __restrict__ Vb,
                                                bf16* __restrict__ O) {
  const int bh = blockIdx.x;
  const int qt = (int)gridDim.y - 1 - (int)blockIdx.y;   // heavy blocks first
  const int tid = threadIdx.x;
  const int l = tid & 63;
  const int w = tid >> 6;

  __shared__ __align__(16) bf16 Ks[64 * 64];   // [kv][dk], swizzled
  __shared__ __align__(16) bf16 Vt[64 * 64];   // [dk][kv], swizzled
  __shared__ __align__(16) bf16 Pl[4][16 * 64];// per-wave [q][kv], swizzled

  const int q0 = qt * 64 + w * 16;
  const int fr  = l & 15;
  const int fkg = l >> 4;                      // 0..3
  const int fkg4 = fkg << 2;
  const size_t base = (size_t)bh * kS * kDK;

  bf16x8 aq[2];
#pragma unroll
  for (int kc = 0; kc < 2; ++kc)
    aq[kc] = *(const bf16x8*)&Q[base + (size_t)(q0 + fr) * kDK + kc * 32 + fkg * 8];

  f32x4 ao[4] = {};
  float m_r = -1e30f, l_r = 0.f;               // state for q = q0 + fr (x4 fkg replicas)

  const int nt = qt + 1;

  const int krow = tid >> 3;                   // 0..31 (+32 second pass)
  const int kcol = (tid & 7) * 8;
  const int dk0  = w * 16;                     // V: wave owns 16 dk cols; lane = kv

  bf16x8 kreg0, kreg1, vreg0, vreg1;
  {
    const size_t kb0 = base + (size_t)krow * kDK + kcol;
    kreg0 = *(const bf16x8*)&Kb[kb0];
    kreg1 = *(const bf16x8*)&Kb[kb0 + 32 * kDK];
    const size_t vb0 = base + (size_t)l * kDK + dk0;
    vreg0 = *(const bf16x8*)&Vb[vb0];
    vreg1 = *(const bf16x8*)&Vb[vb0 + 8];
  }

  for (int j = 0; j < nt; ++j) {
    {
      const int r0 = krow, r1 = krow + 32;
      *(bf16x8*)&Ks[r0 * 64 + (kcol ^ ((r0 & 7) << 3))] = kreg0;
      *(bf16x8*)&Ks[r1 * 64 + (kcol ^ ((r1 & 7) << 3))] = kreg1;
#pragma unroll
      for (int e = 0; e < 8; ++e) {
        const int d0 = dk0 + e, d1 = dk0 + 8 + e;
        Vt[d0 * 64 + (l ^ ((d0 & 7) << 3))] = vreg0[e];
        Vt[d1 * 64 + (l ^ ((d1 & 7) << 3))] = vreg1[e];
      }
    }
    __syncthreads();

    if (j + 1 < nt) {
      const size_t kb0 = base + (size_t)((j + 1) * 64 + krow) * kDK + kcol;
      kreg0 = *(const bf16x8*)&Kb[kb0];
      kreg1 = *(const bf16x8*)&Kb[kb0 + 32 * kDK];
      const size_t vb0 = base + (size_t)((j + 1) * 64 + l) * kDK + dk0;
      vreg0 = *(const bf16x8*)&Vb[vb0];
      vreg1 = *(const bf16x8*)&Vb[vb0 + 8];
    }

    const bool diag = (j == nt - 1);

    // ---- scores (swapped): sc[nf] row = k, col = q = fr ----
    f32x4 sc[4] = {};
#pragma unroll
    for (int nf = 0; nf < 4; ++nf) {
      if (!diag || nf <= w) {
#pragma unroll
        for (int kc = 0; kc < 2; ++kc) {
          const int row = nf * 16 + fr;
          bf16x8 bk = *(const bf16x8*)&Ks[row * 64 + ((kc * 32 + fkg * 8) ^ ((row & 7) << 3))];
          sc[nf] = __builtin_amdgcn_mfma_f32_16x16x32_bf16(bk, aq[kc], sc[nf], 0, 0, 0);
        }
      }
    }

    // ---- online softmax, base-2 (scale pre-folded into Q), defer-max ----
    const int qloc = w * 16 + fr;
    float p[4][4];
    float mx = -INFINITY;
#pragma unroll
    for (int nf = 0; nf < 4; ++nf)
#pragma unroll
      for (int r = 0; r < 4; ++r) {
        float s = sc[nf][r];
        if (diag && (nf * 16 + fkg4 + r) > qloc) s = -INFINITY;
        p[nf][r] = s;
        mx = fmaxf(mx, s);
      }
    mx = fmaxf(mx, __shfl_xor(mx, 16));
    mx = fmaxf(mx, __shfl_xor(mx, 32));

    if (__any(mx > m_r + 11.5f)) {             // rescale only when max grew (T13)
      const float mnew = fmaxf(m_r, mx);
      const float sf = __builtin_amdgcn_exp2f(m_r - mnew);
      l_r *= sf;
      m_r = mnew;
#pragma unroll
      for (int r = 0; r < 4; ++r) {
        const float sfq = __shfl(sf, (l & 48) + fkg4 + r);
#pragma unroll
        for (int n = 0; n < 4; ++n) ao[n][r] *= sfq;
      }
    }

    float rs = 0.f;
#pragma unroll
    for (int nf = 0; nf < 4; ++nf)
#pragma unroll
      for (int r = 0; r < 4; ++r) {
        p[nf][r] = __builtin_amdgcn_exp2f(p[nf][r] - m_r);
        rs += p[nf][r];
      }
    rs += __shfl_xor(rs, 16);
    rs += __shfl_xor(rs, 32);
    l_r += rs;

    // ---- P -> per-wave LDS: lane holds P[k = nf*16+fkg4+r][q = fr] ----
#pragma unroll
    for (int nf = 0; nf < 4; ++nf) {
      bf16x4 p4;
#pragma unroll
      for (int r = 0; r < 4; ++r) p4[r] = (bf16)p[nf][r];
      *(bf16x4*)&Pl[w][fr * 64 + ((nf * 16 + fkg4) ^ ((fr & 7) << 3))] = p4;
    }
    bf16x8 pa[2];
#pragma unroll
    for (int kc2 = 0; kc2 < 2; ++kc2)
      pa[kc2] = *(const bf16x8*)&Pl[w][fr * 64 + ((kc2 * 32 + fkg * 8) ^ ((fr & 7) << 3))];

    // ---- PV ----
#pragma unroll
    for (int kc2 = 0; kc2 < 2; ++kc2) {
      if (kc2 == 0 || !diag || w >= 2) {
#pragma unroll
        for (int n = 0; n < 4; ++n) {
          const int row = n * 16 + fr;
          bf16x8 bv = *(const bf16x8*)&Vt[row * 64 + ((kc2 * 32 + fkg * 8) ^ ((row & 7) << 3))];
          ao[n] = __builtin_amdgcn_mfma_f32_16x16x32_bf16(pa[kc2], bv, ao[n], 0, 0, 0);
        }
      }
    }
    __syncthreads();
  }

  // ---- write O: ao[n][r] is O[q = q0 + fkg4 + r][dk = n*16 + fr] ----
  const int b = bh >> 4, h = bh & 15;
  float lq[4];
#pragma unroll
  for (int r = 0; r < 4; ++r) lq[r] = __shfl(l_r, (l & 48) + fkg4 + r);
#pragma unroll
  for (int n = 0; n < 4; ++n)
#pragma unroll
    for (int r = 0; r < 4; ++r) {
      const int qg = q0 + fkg4 + r;
      const float ov = ao[n][r] / lq[r];
      O[((size_t)(b * kS + qg) << 10) + h * 64 + n * 16 + fr] = (bf16)ov;
    }
}

// ---------------- launch ----------------
extern "C" void kernel_launch(void* const* d_in, const int* in_sizes, int n_in,
                              void* d_out, int out_size, void* d_ws, size_t ws_size,
                              hipStream_t stream) {
  const float* x  = (const float*)d_in[0];
  const float* wq = (const float*)d_in[1];
  const float* wk = (const float*)d_in[2];
  const float* wv = (const float*)d_in[3];
  const float* wo = (const float*)d_in[4];
  const int* pos  = (const int*)d_in[5];

  bf16* xb  = (bf16*)d_ws;                          // [8192][1024]
  bf16* wqb = xb  + (size_t)kM * kD;
  bf16* wkb = wqb + (size_t)kD * kD;
  bf16* wvb = wkb + (size_t)kD * kD;
  bf16* wob = wvb + (size_t)kD * kD;
  bf16* Qb  = wob + (size_t)kD * kD;                // [64][2048][64]
  bf16* Kbf = Qb  + (size_t)64 * kS * kDK;
  bf16* Vbf = Kbf + (size_t)64 * kS * kDK;
  bf16* Ob  = Vbf + (size_t)64 * kS * kDK;          // [8192][1024]

  {
    int n4 = kM * kD / 4;
    cvt_f32_bf16<<<(n4 + 255) / 256, 256, 0, stream>>>(x, xb, n4);
    n4 = kD * kD / 4;
    cvt_w4<<<dim3((n4 + 255) / 256, 4), 256, 0, stream>>>(wq, wk, wv, wo, wqb, wkb, wvb, wob, n4);
  }

  // fused QKV: 128x128 tiles, BK=64 -> grid (64, 24)
  gemm_qkv<<<dim3(kM / 128, 24), 256, 0, stream>>>(xb, wqb, wkb, wvb, Qb, Kbf, Vbf, kD);

  const int np = 64 * kS * 32;
  rope_kernel<<<(2 * np) / 256, 256, 0, stream>>>(Qb, Kbf, pos, np);

  dim3 ga(64, kS / 64);          // (bh, qtile)
  attn_fwd<<<ga, 256, 0, stream>>>(Qb, Kbf, Vbf, Ob);

  // WO: 128x128 tiles, BK=64 -> grid (64, 8)
  gemm_k<128><<<dim3(kM / 128, kD / 128), 256, 0, stream>>>(Ob, wob, d_out, kD, 1);
}

// Round 8
// 277.978 us; speedup vs baseline: 1.7721x; 1.0023x over previous
//
#include <hip/hip_runtime.h>
#include <hip/hip_bf16.h>
#include <stdint.h>
#include <math.h>

// Problem constants: B=4, S=2048, D=1024, H=16, DK=64
static constexpr int kS  = 2048;
static constexpr int kH  = 16;
static constexpr int kDK = 64;
static constexpr int kD  = 1024;
static constexpr int kB  = 4;
static constexpr int kM  = kB * kS;   // 8192 tokens

typedef __bf16 bf16;
typedef __attribute__((ext_vector_type(8))) __bf16 bf16x8;
typedef __attribute__((ext_vector_type(4))) __bf16 bf16x4;
typedef __attribute__((ext_vector_type(4))) float f32x4;

__device__ __forceinline__ void gload_lds16(const bf16* g, bf16* l) {
  __builtin_amdgcn_global_load_lds((__attribute__((address_space(1))) void*)(void*)g,
                                   (__attribute__((address_space(3))) void*)l, 16, 0, 0);
}

// ---------------- fp32 -> bf16 converts ----------------
__global__ void cvt_f32_bf16(const float* __restrict__ in, bf16* __restrict__ out, int n4) {
  int i = blockIdx.x * blockDim.x + threadIdx.x;
  if (i >= n4) return;
  float4 v = reinterpret_cast<const float4*>(in)[i];
  bf16x4 o;
  o[0] = (bf16)v.x; o[1] = (bf16)v.y; o[2] = (bf16)v.z; o[3] = (bf16)v.w;
  reinterpret_cast<bf16x4*>(out)[i] = o;
}

__global__ void cvt_w4(const float* __restrict__ w0, const float* __restrict__ w1,
                       const float* __restrict__ w2, const float* __restrict__ w3,
                       bf16* __restrict__ o0, bf16* __restrict__ o1,
                       bf16* __restrict__ o2, bf16* __restrict__ o3, int n4) {
  int i = blockIdx.x * blockDim.x + threadIdx.x;
  if (i >= n4) return;
  const int sel = blockIdx.y;
  const float* in = (sel == 0) ? w0 : (sel == 1) ? w1 : (sel == 2) ? w2 : w3;
  bf16* out      = (sel == 0) ? o0 : (sel == 1) ? o1 : (sel == 2) ? o2 : o3;
  float4 v = reinterpret_cast<const float4*>(in)[i];
  bf16x4 o;
  o[0] = (bf16)v.x; o[1] = (bf16)v.y; o[2] = (bf16)v.z; o[3] = (bf16)v.w;
  reinterpret_cast<bf16x4*>(out)[i] = o;
}

// ---------------- GEMM: out[m][n] = sum_k A[m][k] * W[n][k] ----------------
// 128x128 tile, BK=32, TRIPLE-buffered LDS, depth-2 prefetch with counted
// vmcnt (T4): per K-step {s_waitcnt vmcnt(4); s_barrier; issue STAGE(t+2);
// ds_read; MFMA}. Batch t+1's 4 loads stay in flight ACROSS the barrier —
// no vmcnt(0) drain in the main loop. Safety: each wave's ds_reads of
// buf[t-1] are lgkm-drained before its MFMAs (compiler-enforced), which
// precede the barrier; post-barrier DMA writes to that slot cannot race.
template<int BM>
__device__ __forceinline__ void gemm_body(const bf16* __restrict__ A,
                                          const bf16* __restrict__ W,
                                          void* __restrict__ dst,
                                          int K, int mode, int brow, int bcol) {
  constexpr int MF  = BM / 32;        // m-frags per wave
  constexpr int ACH = BM / 64;        // A 16-row chunks per wave

  __shared__ __align__(16) bf16 As[3][BM * 32];
  __shared__ __align__(16) bf16 Bs[3][128 * 32];

  const int tid = threadIdx.x;
  const int l   = tid & 63;
  const int w   = tid >> 6;                 // wave 0..3
  const int wr = (w >> 1) * (BM / 2);
  const int wc = (w & 1) * 64;

  f32x4 acc[MF][4] = {};

  const int lrow = l >> 2;                  // 0..15
  const int lcol = (l & 3) * 8;             // 0/8/16/24
  const int fr  = l & 15;
  const int fk  = (l >> 4) * 8;

  const int nk = K >> 5;                    // BK=32 steps

  auto STAGE = [&](int buf, int kt) {
    const int k0 = kt << 5;
#pragma unroll
    for (int c2 = 0; c2 < ACH; ++c2) {
      const int c = w * ACH + c2;
      gload_lds16(A + (size_t)(brow + c * 16 + lrow) * K + k0 + lcol, &As[buf][c * 512]);
    }
#pragma unroll
    for (int c2 = 0; c2 < 2; ++c2) {
      const int c = w * 2 + c2;
      gload_lds16(W + (size_t)(bcol + c * 16 + lrow) * K + k0 + lcol, &Bs[buf][c * 512]);
    }
  };

  STAGE(0, 0);
  STAGE(1, 1);

  int cur = 0;
  for (int kt = 0; kt < nk; ++kt) {
    // wait for batch kt (4 loads/wave/stage; batch kt+1 stays in flight)
    if (kt + 1 < nk) { asm volatile("s_waitcnt vmcnt(4)" ::: "memory"); }
    else             { asm volatile("s_waitcnt vmcnt(0)" ::: "memory"); }
    __builtin_amdgcn_s_barrier();
    __builtin_amdgcn_sched_barrier(0);      // pin: no reads hoisted above barrier

    if (kt + 2 < nk) {
      int s2 = cur + 2; if (s2 >= 3) s2 -= 3;
      STAGE(s2, kt + 2);
    }

    bf16x8 af[MF], bfm[4];
#pragma unroll
    for (int m = 0; m < MF; ++m) af[m]  = *(const bf16x8*)&As[cur][(wr + m * 16 + fr) * 32 + fk];
#pragma unroll
    for (int n = 0; n < 4; ++n)  bfm[n] = *(const bf16x8*)&Bs[cur][(wc + n * 16 + fr) * 32 + fk];
#pragma unroll
    for (int m = 0; m < MF; ++m)
#pragma unroll
      for (int n = 0; n < 4; ++n)
        acc[m][n] = __builtin_amdgcn_mfma_f32_16x16x32_bf16(af[m], bfm[n], acc[m][n], 0, 0, 0);

    cur = (cur + 1 == 3) ? 0 : cur + 1;
  }

  const int frow = (l >> 4) * 4;
  if (mode == 0) {
    bf16* out = (bf16*)dst;
#pragma unroll
    for (int m = 0; m < MF; ++m) {
#pragma unroll
      for (int n = 0; n < 4; ++n) {
        const int col = bcol + wc + n * 16 + fr;
        const int h = col >> 6, dk = col & 63;
#pragma unroll
        for (int r = 0; r < 4; ++r) {
          const int row = brow + wr + m * 16 + frow + r;
          const int b = row >> 11, s = row & (kS - 1);
          out[((((size_t)b * kH + h) * kS + s) << 6) + dk] = (bf16)acc[m][n][r];
        }
      }
    }
  } else {
    float* out = (float*)dst;
#pragma unroll
    for (int m = 0; m < MF; ++m) {
#pragma unroll
      for (int n = 0; n < 4; ++n) {
        const int col = bcol + wc + n * 16 + fr;
#pragma unroll
        for (int r = 0; r < 4; ++r) {
          const int row = brow + wr + m * 16 + frow + r;
          out[(size_t)row * kD + col] = acc[m][n][r];
        }
      }
    }
  }
}

template<int BM>
__global__ __launch_bounds__(256) void gemm_k(const bf16* __restrict__ A,
                                              const bf16* __restrict__ W,
                                              void* __restrict__ dst, int K, int mode) {
  gemm_body<BM>(A, W, dst, K, mode, blockIdx.x * BM, blockIdx.y * 128);
}

// Fused QKV: grid (kM/128, 24); by>>3 selects Q/K/V, by&7 the 128-col block.
__global__ __launch_bounds__(256) void gemm_qkv(const bf16* __restrict__ A,
                                                const bf16* __restrict__ wq,
                                                const bf16* __restrict__ wk,
                                                const bf16* __restrict__ wv,
                                                bf16* __restrict__ Qb,
                                                bf16* __restrict__ Kb,
                                                bf16* __restrict__ Vb, int K) {
  const int by = blockIdx.y;
  const int sel = by >> 3;
  const bf16* W = (sel == 0) ? wq : (sel == 1) ? wk : wv;
  bf16* dst     = (sel == 0) ? Qb : (sel == 1) ? Kb : Vb;
  gemm_body<128>(A, W, dst, K, 0, blockIdx.x * 128, (by & 7) * 128);
}

// ---------------- RoPE, in-place; Q pre-scaled by 1/8*log2e ----------------
// HW v_sin/v_cos (input in revolutions, fract range-reduction) — arg rounding
// ~2e-4 rad, same order as the f32 reference's own ulp at pos~2047.
__global__ void rope_kernel(bf16* __restrict__ Q, bf16* __restrict__ Kb,
                            const int* __restrict__ pos, int np) {
  int idx = blockIdx.x * blockDim.x + threadIdx.x;
  if (idx >= 2 * np) return;
  const bool isQ = (idx < np);
  bf16* T = isQ ? Q : Kb;
  int id = isQ ? idx : idx - np;
  const int i = id & 31;
  const int s = (id >> 5) & (kS - 1);
  const float p = (float)pos[s];
  const float freq = __expf(-0.2878231366242557f * (float)i);
  const float frev = p * freq * 0.15915494309189535f;   // radians -> revolutions
  const float r = frev - floorf(frev);
  const float sn = __builtin_amdgcn_sinf(r);
  const float cs = __builtin_amdgcn_cosf(r);
  const float sc = isQ ? (0.125f * 1.4426950408889634f) : 1.0f;
  const size_t off = (size_t)id * 2;
  const float e = (float)T[off], o = (float)T[off + 1];
  T[off]     = (bf16)((e * cs - o * sn) * sc);
  T[off + 1] = (bf16)((o * cs + e * sn) * sc);
}

// ---------------- causal flash attention v4 (unchanged from round 7) ----------------
__global__ __launch_bounds__(256) void attn_fwd(const bf16* __restrict__ Q,
                                                const bf16* __restrict__ Kb,
                                                const bf16* __restrict__ Vb,
                                                bf16* __restrict__ O) {
  const int bh = blockIdx.x;
  const int qt = (int)gridDim.y - 1 - (int)blockIdx.y;   // heavy blocks first
  const int tid = threadIdx.x;
  const int l = tid & 63;
  const int w = tid >> 6;

  __shared__ __align__(16) bf16 Ks[64 * 64];   // [kv][dk], swizzled
  __shared__ __align__(16) bf16 Vt[64 * 64];   // [dk][kv], swizzled
  __shared__ __align__(16) bf16 Pl[4][16 * 64];// per-wave [q][kv], swizzled

  const int q0 = qt * 64 + w * 16;
  const int fr  = l & 15;
  const int fkg = l >> 4;                      // 0..3
  const int fkg4 = fkg << 2;
  const size_t base = (size_t)bh * kS * kDK;

  bf16x8 aq[2];
#pragma unroll
  for (int kc = 0; kc < 2; ++kc)
    aq[kc] = *(const bf16x8*)&Q[base + (size_t)(q0 + fr) * kDK + kc * 32 + fkg * 8];

  f32x4 ao[4] = {};
  float m_r = -1e30f, l_r = 0.f;               // state for q = q0 + fr (x4 fkg replicas)

  const int nt = qt + 1;

  const int krow = tid >> 3;                   // 0..31 (+32 second pass)
  const int kcol = (tid & 7) * 8;
  const int dk0  = w * 16;                     // V: wave owns 16 dk cols; lane = kv

  bf16x8 kreg0, kreg1, vreg0, vreg1;
  {
    const size_t kb0 = base + (size_t)krow * kDK + kcol;
    kreg0 = *(const bf16x8*)&Kb[kb0];
    kreg1 = *(const bf16x8*)&Kb[kb0 + 32 * kDK];
    const size_t vb0 = base + (size_t)l * kDK + dk0;
    vreg0 = *(const bf16x8*)&Vb[vb0];
    vreg1 = *(const bf16x8*)&Vb[vb0 + 8];
  }

  for (int j = 0; j < nt; ++j) {
    {
      const int r0 = krow, r1 = krow + 32;
      *(bf16x8*)&Ks[r0 * 64 + (kcol ^ ((r0 & 7) << 3))] = kreg0;
      *(bf16x8*)&Ks[r1 * 64 + (kcol ^ ((r1 & 7) << 3))] = kreg1;
#pragma unroll
      for (int e = 0; e < 8; ++e) {
        const int d0 = dk0 + e, d1 = dk0 + 8 + e;
        Vt[d0 * 64 + (l ^ ((d0 & 7) << 3))] = vreg0[e];
        Vt[d1 * 64 + (l ^ ((d1 & 7) << 3))] = vreg1[e];
      }
    }
    __syncthreads();

    if (j + 1 < nt) {
      const size_t kb0 = base + (size_t)((j + 1) * 64 + krow) * kDK + kcol;
      kreg0 = *(const bf16x8*)&Kb[kb0];
      kreg1 = *(const bf16x8*)&Kb[kb0 + 32 * kDK];
      const size_t vb0 = base + (size_t)((j + 1) * 64 + l) * kDK + dk0;
      vreg0 = *(const bf16x8*)&Vb[vb0];
      vreg1 = *(const bf16x8*)&Vb[vb0 + 8];
    }

    const bool diag = (j == nt - 1);

    // ---- scores (swapped): sc[nf] row = k, col = q = fr ----
    f32x4 sc[4] = {};
#pragma unroll
    for (int nf = 0; nf < 4; ++nf) {
      if (!diag || nf <= w) {
#pragma unroll
        for (int kc = 0; kc < 2; ++kc) {
          const int row = nf * 16 + fr;
          bf16x8 bk = *(const bf16x8*)&Ks[row * 64 + ((kc * 32 + fkg * 8) ^ ((row & 7) << 3))];
          sc[nf] = __builtin_amdgcn_mfma_f32_16x16x32_bf16(bk, aq[kc], sc[nf], 0, 0, 0);
        }
      }
    }

    // ---- online softmax, base-2 (scale pre-folded into Q), defer-max ----
    const int qloc = w * 16 + fr;
    float p[4][4];
    float mx = -INFINITY;
#pragma unroll
    for (int nf = 0; nf < 4; ++nf)
#pragma unroll
      for (int r = 0; r < 4; ++r) {
        float s = sc[nf][r];
        if (diag && (nf * 16 + fkg4 + r) > qloc) s = -INFINITY;
        p[nf][r] = s;
        mx = fmaxf(mx, s);
      }
    mx = fmaxf(mx, __shfl_xor(mx, 16));
    mx = fmaxf(mx, __shfl_xor(mx, 32));

    if (__any(mx > m_r + 11.5f)) {             // rescale only when max grew (T13)
      const float mnew = fmaxf(m_r, mx);
      const float sf = __builtin_amdgcn_exp2f(m_r - mnew);
      l_r *= sf;
      m_r = mnew;
#pragma unroll
      for (int r = 0; r < 4; ++r) {
        const float sfq = __shfl(sf, (l & 48) + fkg4 + r);
#pragma unroll
        for (int n = 0; n < 4; ++n) ao[n][r] *= sfq;
      }
    }

    float rs = 0.f;
#pragma unroll
    for (int nf = 0; nf < 4; ++nf)
#pragma unroll
      for (int r = 0; r < 4; ++r) {
        p[nf][r] = __builtin_amdgcn_exp2f(p[nf][r] - m_r);
        rs += p[nf][r];
      }
    rs += __shfl_xor(rs, 16);
    rs += __shfl_xor(rs, 32);
    l_r += rs;

    // ---- P -> per-wave LDS: lane holds P[k = nf*16+fkg4+r][q = fr] ----
#pragma unroll
    for (int nf = 0; nf < 4; ++nf) {
      bf16x4 p4;
#pragma unroll
      for (int r = 0; r < 4; ++r) p4[r] = (bf16)p[nf][r];
      *(bf16x4*)&Pl[w][fr * 64 + ((nf * 16 + fkg4) ^ ((fr & 7) << 3))] = p4;
    }
    bf16x8 pa[2];
#pragma unroll
    for (int kc2 = 0; kc2 < 2; ++kc2)
      pa[kc2] = *(const bf16x8*)&Pl[w][fr * 64 + ((kc2 * 32 + fkg * 8) ^ ((fr & 7) << 3))];

    // ---- PV ----
#pragma unroll
    for (int kc2 = 0; kc2 < 2; ++kc2) {
      if (kc2 == 0 || !diag || w >= 2) {
#pragma unroll
        for (int n = 0; n < 4; ++n) {
          const int row = n * 16 + fr;
          bf16x8 bv = *(const bf16x8*)&Vt[row * 64 + ((kc2 * 32 + fkg * 8) ^ ((row & 7) << 3))];
          ao[n] = __builtin_amdgcn_mfma_f32_16x16x32_bf16(pa[kc2], bv, ao[n], 0, 0, 0);
        }
      }
    }
    __syncthreads();
  }

  // ---- write O: ao[n][r] is O[q = q0 + fkg4 + r][dk = n*16 + fr] ----
  const int b = bh >> 4, h = bh & 15;
  float lq[4];
#pragma unroll
  for (int r = 0; r < 4; ++r) lq[r] = __shfl(l_r, (l & 48) + fkg4 + r);
#pragma unroll
  for (int n = 0; n < 4; ++n)
#pragma unroll
    for (int r = 0; r < 4; ++r) {
      const int qg = q0 + fkg4 + r;
      const float ov = ao[n][r] / lq[r];
      O[((size_t)(b * kS + qg) << 10) + h * 64 + n * 16 + fr] = (bf16)ov;
    }
}

// ---------------- launch ----------------
extern "C" void kernel_launch(void* const* d_in, const int* in_sizes, int n_in,
                              void* d_out, int out_size, void* d_ws, size_t ws_size,
                              hipStream_t stream) {
  const float* x  = (const float*)d_in[0];
  const float* wq = (const float*)d_in[1];
  const float* wk = (const float*)d_in[2];
  const float* wv = (const float*)d_in[3];
  const float* wo = (const float*)d_in[4];
  const int* pos  = (const int*)d_in[5];

  bf16* xb  = (bf16*)d_ws;                          // [8192][1024]
  bf16* wqb = xb  + (size_t)kM * kD;
  bf16* wkb = wqb + (size_t)kD * kD;
  bf16* wvb = wkb + (size_t)kD * kD;
  bf16* wob = wvb + (size_t)kD * kD;
  bf16* Qb  = wob + (size_t)kD * kD;                // [64][2048][64]
  bf16* Kbf = Qb  + (size_t)64 * kS * kDK;
  bf16* Vbf = Kbf + (size_t)64 * kS * kDK;
  bf16* Ob  = Vbf + (size_t)64 * kS * kDK;          // [8192][1024]

  {
    int n4 = kM * kD / 4;
    cvt_f32_bf16<<<(n4 + 255) / 256, 256, 0, stream>>>(x, xb, n4);
    n4 = kD * kD / 4;
    cvt_w4<<<dim3((n4 + 255) / 256, 4), 256, 0, stream>>>(wq, wk, wv, wo, wqb, wkb, wvb, wob, n4);
  }

  // fused QKV: 128x128 tiles, BK=32 depth-2 pipeline -> grid (64, 24)
  gemm_qkv<<<dim3(kM / 128, 24), 256, 0, stream>>>(xb, wqb, wkb, wvb, Qb, Kbf, Vbf, kD);

  const int np = 64 * kS * 32;
  rope_kernel<<<(2 * np) / 256, 256, 0, stream>>>(Qb, Kbf, pos, np);

  dim3 ga(64, kS / 64);          // (bh, qtile)
  attn_fwd<<<ga, 256, 0, stream>>>(Qb, Kbf, Vbf, Ob);

  // WO: 128x128 tiles -> grid (64, 8)
  gemm_k<128><<<dim3(kM / 128, kD / 128), 256, 0, stream>>>(Ob, wob, d_out, kD, 1);
}